// Round 15
// baseline (719.834 us; speedup 1.0000x reference)
//
#include <hip/hip_runtime.h>
#include <hip/hip_bf16.h>
#include <math.h>

#define NB 4
#define HEADS 8
#define DIM 512
#define MLP 2048
#define NT 2048
#define DH 64
#define M_TOK (NB*NT)

typedef __bf16 bf16;
typedef __bf16 bf16x2 __attribute__((ext_vector_type(2)));
typedef __bf16 bf16x4 __attribute__((ext_vector_type(4)));
typedef __bf16 bf16x8 __attribute__((ext_vector_type(8)));
typedef float f32x4 __attribute__((ext_vector_type(4)));

__device__ __forceinline__ void gl_lds16(const void* g, void* l) {
    __builtin_amdgcn_global_load_lds((const __attribute__((address_space(1))) unsigned int*)g,
                                     (__attribute__((address_space(3))) unsigned int*)l, 16, 0, 0);
}

#define BARRIER() do { __builtin_amdgcn_s_barrier(); asm volatile("" ::: "memory"); } while(0)
#define WAIT_VM4() asm volatile("s_waitcnt vmcnt(4)" ::: "memory")
#define WAIT_VM0() asm volatile("s_waitcnt vmcnt(0)" ::: "memory")

// tanh-form GELU: ~8 VALU instrs vs erff's ~20+; max |err| ~5e-4; exact at +-inf.
__device__ __forceinline__ float fast_gelu(float u) {
    float u2 = u * u;
    float y  = u * __builtin_fmaf(u2, 0.044715f, 1.0f);
    float e  = exp2f(y * 2.3021839f);          // exp(2*0.79788456*y)
    float r  = __builtin_amdgcn_rcpf(e + 1.0f);
    return u - u * r;                           // u * e/(e+1)
}

// ---------------- fp32 -> bf16 weight conversion ----------------
__global__ void cvt_bf16_kernel(const float* __restrict__ src, bf16* __restrict__ dst, int n) {
    int i = (blockIdx.x * 256 + threadIdx.x) * 4;
    if (i < n) {
        float4 v = *(const float4*)(src + i);
        bf16x4 o;
        o[0] = (bf16)v.x; o[1] = (bf16)v.y; o[2] = (bf16)v.z; o[3] = (bf16)v.w;
        *(bf16x4*)(dst + i) = o;
    }
}

// ---------------- LayerNorm (one wave per row of 512) ----------------
__global__ void ln_kernel(const float* __restrict__ X, const float* __restrict__ gam,
                          const float* __restrict__ bet, bf16* __restrict__ out) {
    int w = threadIdx.x >> 6, l = threadIdx.x & 63;
    long row = (long)blockIdx.x * 4 + w;
    const float* xp = X + row * DIM + l * 8;
    float4 a = *(const float4*)xp;
    float4 b = *(const float4*)(xp + 4);
    float s1 = a.x + a.y + a.z + a.w + b.x + b.y + b.z + b.w;
    float s2 = a.x*a.x + a.y*a.y + a.z*a.z + a.w*a.w + b.x*b.x + b.y*b.y + b.z*b.z + b.w*b.w;
#pragma unroll
    for (int off = 32; off; off >>= 1) { s1 += __shfl_xor(s1, off); s2 += __shfl_xor(s2, off); }
    float mean = s1 * (1.f / 512.f);
    float var  = s2 * (1.f / 512.f) - mean * mean;
    float rstd = rsqrtf(var + 1e-5f);
    float4 g0 = *(const float4*)(gam + l * 8), g1 = *(const float4*)(gam + l * 8 + 4);
    float4 b0 = *(const float4*)(bet + l * 8), b1 = *(const float4*)(bet + l * 8 + 4);
    bf16x8 o;
    o[0] = (bf16)((a.x - mean) * rstd * g0.x + b0.x);
    o[1] = (bf16)((a.y - mean) * rstd * g0.y + b0.y);
    o[2] = (bf16)((a.z - mean) * rstd * g0.z + b0.z);
    o[3] = (bf16)((a.w - mean) * rstd * g0.w + b0.w);
    o[4] = (bf16)((b.x - mean) * rstd * g1.x + b1.x);
    o[5] = (bf16)((b.y - mean) * rstd * g1.y + b1.y);
    o[6] = (bf16)((b.z - mean) * rstd * g1.z + b1.z);
    o[7] = (bf16)((b.w - mean) * rstd * g1.w + b1.w);
    *(bf16x8*)(out + row * DIM + l * 8) = o;
}

// ================= 128x128 8-phase GEMM (4 waves, BK=64, dbuf) — qkv / fc1 =================
#define G_LOADA(AF, B_, MQ) do { \
  _Pragma("unroll") for (int mi_ = 0; mi_ < 2; ++mi_) \
  _Pragma("unroll") for (int kk_ = 0; kk_ < 2; ++kk_) { \
    int row_ = wr * 64 + ((MQ) * 2 + mi_) * 16 + c; \
    AF[mi_][kk_] = *(const bf16x8*)&Abuf[B_][row_ * 64 + (((kk_ * 64 + g * 16) ^ sw) >> 1)]; \
  } } while (0)

#define G_LOADB(BF, B_, NQ) do { \
  _Pragma("unroll") for (int ni_ = 0; ni_ < 2; ++ni_) \
  _Pragma("unroll") for (int kk_ = 0; kk_ < 2; ++kk_) { \
    int row_ = wc * 64 + ((NQ) * 2 + ni_) * 16 + c; \
    BF[ni_][kk_] = *(const bf16x8*)&Bbuf[B_][row_ * 64 + (((kk_ * 64 + g * 16) ^ sw) >> 1)]; \
  } } while (0)

#define G_MFMA(AF, BF, MQ, NQ) do { \
  __builtin_amdgcn_s_setprio(1); \
  _Pragma("unroll") for (int mi_ = 0; mi_ < 2; ++mi_) \
  _Pragma("unroll") for (int ni_ = 0; ni_ < 2; ++ni_) \
  _Pragma("unroll") for (int kk_ = 0; kk_ < 2; ++kk_) \
    acc[(MQ)*2+mi_][(NQ)*2+ni_] = __builtin_amdgcn_mfma_f32_16x16x32_bf16( \
        AF[mi_][kk_], BF[ni_][kk_], acc[(MQ)*2+mi_][(NQ)*2+ni_], 0, 0, 0); \
  __builtin_amdgcn_s_setprio(0); \
} while (0)

#define G_STAGE_A(J_, H_) do { int j_ = (J_); if (j_ < nkt) { \
  bf16* db_ = Abuf[j_ & 1]; const bf16* sb_ = Aptr + (size_t)j_ * 64 + coloff; \
  _Pragma("unroll") for (int q_ = 0; q_ < 2; ++q_) { \
    int rw_ = q_ * 64 + (H_) * 32 + (w << 3); \
    gl_lds16(sb_ + (size_t)(arow0 + rw_ + lr) * KN, db_ + rw_ * 64); \
  } } } while (0)

#define G_STAGE_B(J_, H_) do { int j_ = (J_); if (j_ < nkt) { \
  bf16* db_ = Bbuf[j_ & 1]; const bf16* sb_ = Wptr + (size_t)j_ * 64 + coloff; \
  _Pragma("unroll") for (int q_ = 0; q_ < 2; ++q_) { \
    int rw_ = q_ * 64 + (H_) * 32 + (w << 3); \
    gl_lds16(sb_ + (size_t)(bcol0 + rw_ + lr) * KN, db_ + rw_ * 64); \
  } } } while (0)

// EPI 0: QKV scatter (Q pre-scaled by 0.125*log2e; V transposed to vt)
// EPI 2: +bias fast-GELU -> bf16 (fc1)
template<int EPI, int KN>
__global__ __launch_bounds__(256, 2) void gemm128(const bf16* __restrict__ Aptr,
                                                  const bf16* __restrict__ Wptr,
                                                  const float* __restrict__ bias,
                                                  const float* __restrict__ resid,
                                                  void* outp, int N, bf16* __restrict__ vtout) {
    __shared__ bf16 Abuf[2][128 * 64];
    __shared__ bf16 Bbuf[2][128 * 64];
    const int t = threadIdx.x, w = t >> 6, l = t & 63;
    const int wr = w >> 1, wc = w & 1, g = l >> 4, c = l & 15;
    const int sw = (c & 7) << 4;
    const int lr = l >> 3;
    const int coloff = ((l & 7) ^ lr) << 3;

    int nwg = gridDim.x, bid = blockIdx.x;
    int q8 = nwg >> 3, r8 = nwg & 7;
    int xcd = bid & 7, rank = bid >> 3;
    int swz = (xcd < r8) ? xcd * (q8 + 1) + rank : r8 * (q8 + 1) + (xcd - r8) * q8 + rank;
    int tiles_n = N >> 7;
    long arow0 = (long)(swz / tiles_n) * 128;
    long bcol0 = (long)(swz % tiles_n) * 128;

    const int nkt = KN / 64;
    const int niter = nkt / 2;
    f32x4 acc[4][4] = {};
    bf16x8 af[2][2], bn0[2][2], bn1[2][2];

    G_STAGE_A(0, 0); G_STAGE_B(0, 0); G_STAGE_A(0, 1); G_STAGE_B(0, 1);
    G_STAGE_A(1, 0); G_STAGE_B(1, 0);

#pragma unroll 1
    for (int tt = 0; tt < niter; ++tt) {
        const int J0 = 2 * tt, J1 = 2 * tt + 1;
        const bool last = (tt == niter - 1);
        WAIT_VM4(); BARRIER();
        G_LOADA(af, 0, 0); G_LOADB(bn0, 0, 0);
        G_STAGE_A(J0 + 1, 1);
        G_MFMA(af, bn0, 0, 0);
        BARRIER();
        G_LOADB(bn1, 0, 1);
        G_STAGE_B(J0 + 1, 1);
        G_MFMA(af, bn1, 0, 1);
        BARRIER();
        G_LOADA(af, 0, 1);
        G_STAGE_A(J0 + 2, 0);
        G_MFMA(af, bn0, 1, 0);
        BARRIER();
        G_STAGE_B(J0 + 2, 0);
        G_MFMA(af, bn1, 1, 1);
        BARRIER();
        if (last) { WAIT_VM0(); } else { WAIT_VM4(); }
        BARRIER();
        G_LOADA(af, 1, 0); G_LOADB(bn0, 1, 0);
        G_STAGE_A(J1 + 1, 1);
        G_MFMA(af, bn0, 0, 0);
        BARRIER();
        G_LOADB(bn1, 1, 1);
        G_STAGE_B(J1 + 1, 1);
        G_MFMA(af, bn1, 0, 1);
        BARRIER();
        G_LOADA(af, 1, 1);
        G_STAGE_A(J1 + 2, 0);
        G_MFMA(af, bn0, 1, 0);
        BARRIER();
        G_STAGE_B(J1 + 2, 0);
        G_MFMA(af, bn1, 1, 1);
        BARRIER();
    }

    if constexpr (EPI == 0) {
        const int s = (int)(bcol0 >> 9);
        const float qscale = 0.18033688011112042f;   // 0.125 * log2(e)
        if (s == 2) {
#pragma unroll
            for (int m = 0; m < 4; ++m)
#pragma unroll
                for (int n = 0; n < 4; ++n) {
                    int col = (int)(bcol0 + wc * 64 + n * 16 + c);
                    int d = col & 63, hh = (col >> 6) & 7;
                    long row = arow0 + wr * 64 + m * 16 + g * 4;
                    int bb = (int)(row >> 11), nn = (int)(row & 2047);
                    bf16x4 o4;
#pragma unroll
                    for (int r = 0; r < 4; ++r) o4[r] = (bf16)acc[m][n][r];
                    *(bf16x4*)(vtout + ((long)(bb * 8 + hh) * 64 + d) * 2048 + nn) = o4;
                }
        } else {
            const float sc = (s == 0) ? qscale : 1.0f;
#pragma unroll
            for (int m = 0; m < 4; ++m)
#pragma unroll
                for (int n = 0; n < 4; ++n) {
                    int col = (int)(bcol0 + wc * 64 + n * 16 + c);
                    int hh = (col >> 6) & 7, d = col & 63;
                    long row = arow0 + wr * 64 + m * 16 + g * 4;
#pragma unroll
                    for (int r = 0; r < 4; ++r) {
                        long rr = row + r;
                        int bb = (int)(rr >> 11), nn = (int)(rr & 2047);
                        ((bf16*)outp)[(((long)(s * NB + bb) * HEADS + hh) * NT + nn) * DH + d] =
                            (bf16)(acc[m][n][r] * sc);
                    }
                }
        }
    } else {
#pragma unroll
        for (int m = 0; m < 4; ++m)
#pragma unroll
            for (int n = 0; n < 4; ++n) {
                long row = arow0 + wr * 64 + m * 16 + g * 4;
                long col = bcol0 + wc * 64 + n * 16 + c;
#pragma unroll
                for (int r = 0; r < 4; ++r) {
                    long rr = row + r;
                    float u = acc[m][n][r] + bias[col];
                    ((bf16*)outp)[rr * N + col] = (bf16)fast_gelu(u);
                }
            }
    }
}

// ======== 128x64-tile 2-phase GEMM (m97 structure), N=512 out (proj / fc2) ========
template<int KN, int NOUT, int EPI>
__global__ __launch_bounds__(256, 2) void gemm_n64(const bf16* __restrict__ A,
                                                   const bf16* __restrict__ W,
                                                   const float* __restrict__ bias,
                                                   const float* __restrict__ resid,
                                                   void* __restrict__ outp) {
    __shared__ bf16 As[128 * 64];
    __shared__ bf16 Bs[64 * 64];
    const int t = threadIdx.x, w = t >> 6, l = t & 63;
    const int wr = w >> 1, wc = w & 1, g = l >> 4, c = l & 15;
    const long arow0 = (long)blockIdx.y * 128;
    const long bcol0 = (long)blockIdx.x * 64;
    f32x4 acc[4][2] = {};
    const int lrow = l >> 3, lcol = (l & 7) * 8;
    const bf16* Ab = A + (arow0 + lrow) * (long)KN + lcol;
    const bf16* Wb = W + (bcol0 + lrow) * (long)KN + lcol;
    for (int k0 = 0; k0 < KN; k0 += 64) {
#pragma unroll
        for (int q = 0; q < 4; ++q)
            gl_lds16(Ab + (long)(w * 4 + q) * 8 * KN + k0, &As[(w * 4 + q) * 512]);
#pragma unroll
        for (int q = 0; q < 2; ++q)
            gl_lds16(Wb + (long)(w * 2 + q) * 8 * KN + k0, &Bs[(w * 2 + q) * 512]);
        __syncthreads();
#pragma unroll
        for (int kk = 0; kk < 2; ++kk) {
            bf16x8 afv[4], bfr[2];
#pragma unroll
            for (int m = 0; m < 4; ++m)
                afv[m] = *(const bf16x8*)&As[(wr * 64 + m * 16 + c) * 64 + kk * 32 + g * 8];
#pragma unroll
            for (int n = 0; n < 2; ++n)
                bfr[n] = *(const bf16x8*)&Bs[(wc * 32 + n * 16 + c) * 64 + kk * 32 + g * 8];
#pragma unroll
            for (int m = 0; m < 4; ++m)
#pragma unroll
                for (int n = 0; n < 2; ++n)
                    acc[m][n] = __builtin_amdgcn_mfma_f32_16x16x32_bf16(afv[m], bfr[n], acc[m][n], 0, 0, 0);
        }
        __syncthreads();
    }
#pragma unroll
    for (int m = 0; m < 4; ++m)
#pragma unroll
        for (int n = 0; n < 2; ++n) {
            long row = arow0 + wr * 64 + m * 16 + g * 4;
            long col = bcol0 + wc * 32 + n * 16 + c;
#pragma unroll
            for (int r = 0; r < 4; ++r) {
                long rr = row + r;
                float v = acc[m][n][r] + bias[col];
                if constexpr (EPI == 1) {
                    ((float*)outp)[rr * NOUT + col] = v + resid[rr * NOUT + col];
                } else {
                    ((bf16*)outp)[rr * NOUT + col] = (bf16)fast_gelu(v);
                }
            }
        }
}

// ---------------- Flash attention v11: two-base imm-offset LDS reads, z4-folded QK ----------------
#define NKT (NT / 64)

#define ATT_STAGE(J_, B_) do { \
    const bf16* ks_ = kbase + (size_t)(J_) * (64 * DH); \
    const bf16* vs_ = vbase + (J_) * 64; \
    gl_lds16(ks_,           &Ks[B_][(w * 8) * 64]); \
    gl_lds16(ks_ + 32 * DH, &Ks[B_][(32 + w * 8) * 64]); \
    gl_lds16(vs_,           &Vs[B_][(w * 8) * 64]); \
    gl_lds16(vs_ + 32 * NT, &Vs[B_][(32 + w * 8) * 64]); \
} while (0)

// QK with C-in = z4 on the first MFMA (no separate accumulator init).
// Byte addressing: row (kc*16+c) stride 128B -> kc*2048 + a0/a1 (a0,a1 in VGPR; rest imm).
#define ATT_QK(B_, ST) do { \
    const char* KB_ = (const char*)&Ks[B_][0]; \
    _Pragma("unroll") for (int kc = 0; kc < 4; ++kc) { \
        bf16x8 k0_ = *(const bf16x8*)(KB_ + a0 + kc * 2048); \
        bf16x8 k1_ = *(const bf16x8*)(KB_ + a1 + kc * 2048); \
        ST[kc] = __builtin_amdgcn_mfma_f32_16x16x32_bf16(k0_, qf[0], z4, 0, 0, 0); \
        ST[kc] = __builtin_amdgcn_mfma_f32_16x16x32_bf16(k1_, qf[1], ST[kc], 0, 0, 0); \
    } \
} while (0)

// body for tile KT (parity BUF == KT&1): vf+exp before barrier; stage(KT+2);
// then setprio cluster {QK(KT+1) -> SOUT, denom, PV(KT) from SIN's pf}.
#define ATT_BODY(BUF, KT, SIN, SOUT) do { \
    const char* VB_ = (const char*)&Vs[BUF][0]; \
    bf16x8 vf[4][2]; \
    _Pragma("unroll") for (int dc = 0; dc < 4; ++dc) { \
        vf[dc][0] = *(const bf16x8*)(VB_ + a0 + dc * 2048); \
        vf[dc][1] = *(const bf16x8*)(VB_ + a1 + dc * 2048); \
    } \
    bf16x8 pf[2]; \
    _Pragma("unroll") for (int a = 0; a < 4; ++a) \
    _Pragma("unroll") for (int r = 0; r < 4; ++r) \
        pf[a >> 1][(a & 1) * 4 + r] = (bf16)exp2f(SIN[a][r]); \
    __syncthreads(); \
    if ((KT) + 2 < NKT) ATT_STAGE((KT) + 2, BUF); \
    __builtin_amdgcn_s_setprio(1); \
    if ((KT) + 1 < NKT) ATT_QK((BUF) ^ 1, SOUT); \
    _Pragma("unroll") for (int ks = 0; ks < 2; ++ks) \
        sacc = __builtin_amdgcn_mfma_f32_16x16x32_bf16(ones8, pf[ks], sacc, 0, 0, 0); \
    _Pragma("unroll") for (int dc = 0; dc < 4; ++dc) \
    _Pragma("unroll") for (int ks = 0; ks < 2; ++ks) \
        oacc[dc] = __builtin_amdgcn_mfma_f32_16x16x32_bf16(vf[dc][ks], pf[ks], oacc[dc], 0, 0, 0); \
    __builtin_amdgcn_s_setprio(0); \
} while (0)

__global__ __launch_bounds__(256, 4) void attn_kernel(const bf16* __restrict__ qkv,
                                                      const bf16* __restrict__ vt,
                                                      bf16* __restrict__ O) {
    __shared__ bf16 Ks[2][64 * 64];
    __shared__ bf16 Vs[2][64 * 64];
    const int t = threadIdx.x, w = t >> 6, l = t & 63;
    const int g = l >> 4, c = l & 15;
    const int wg = blockIdx.x;
    const int xcd = wg & 7, rank = wg >> 3;
    const int bh = xcd + 8 * (rank >> 5);
    const int qt = rank & 31;
    const bf16* Qb = qkv + (long)bh * (NT * DH);
    const bf16* Kb = Qb + (long)(NB * HEADS) * (NT * DH);
    const bf16* Vtb = vt + (long)bh * (DH * NT);
    const int q0 = qt * 64 + w * 16;
    const int lr = l >> 3, lc = l & 7;
    const int sch = ((lc ^ lr) & 7) * 8;
    const int xr = (c & 7) << 4;
    // two dynamic LDS byte-offsets; per-kc/dc deltas are compile-time (fold into ds_read imm)
    const int a0 = c * 128 + ((g * 16) ^ xr);
    const int a1 = c * 128 + ((64 + g * 16) ^ xr);

    const bf16* kbase = Kb + (long)(w * 8 + lr) * DH + sch;
    const bf16* vbase = Vtb + (long)(w * 8 + lr) * NT + sch;

    bf16x8 qf[2];
#pragma unroll
    for (int kk = 0; kk < 2; ++kk)
        qf[kk] = *(const bf16x8*)(Qb + (long)(q0 + c) * DH + kk * 32 + g * 8);

    bf16x8 ones8;
#pragma unroll
    for (int j = 0; j < 8; ++j) ones8[j] = (bf16)1.0f;
    const f32x4 z4 = {};

    f32x4 oacc[4] = {};
    f32x4 sacc = {};
    f32x4 st0[4], st1[4];

    ATT_STAGE(0, 0);
    ATT_STAGE(1, 1);
    __syncthreads();
    ATT_QK(0, st0);

#pragma unroll 1
    for (int kt2 = 0; kt2 < NKT / 2; ++kt2) {
        ATT_BODY(0, kt2 * 2,     st0, st1);
        ATT_BODY(1, kt2 * 2 + 1, st1, st0);
    }

    float inv = 1.f / sacc[0];

    char* ol = (char*)&Ks[0][0] + w * 2048;
#pragma unroll
    for (int dc = 0; dc < 4; ++dc) {
        bf16x4 o4;
#pragma unroll
        for (int r = 0; r < 4; ++r) o4[r] = (bf16)(oacc[dc][r] * inv);
        *(bf16x4*)(ol + c * 128 + ((dc * 32 + g * 8) ^ xr)) = o4;
    }
    __builtin_amdgcn_s_waitcnt(0);  // lgkmcnt(0): wave-private region
    const int orow = l >> 2, oc = (l & 3) * 16;
    const int bb = bh >> 3, hh = bh & 7;
    long tok = (long)bb * NT + q0 + orow;
    bf16* og = O + tok * DIM + hh * 64 + oc;
    const int xr2 = (orow & 7) << 4;
    bf16x8 v0 = *(const bf16x8*)(ol + orow * 128 + ((oc * 2) ^ xr2));
    bf16x8 v1 = *(const bf16x8*)(ol + orow * 128 + ((oc * 2 + 16) ^ xr2));
    *(bf16x8*)og = v0;
    *(bf16x8*)(og + 8) = v1;
}

extern "C" void kernel_launch(void* const* d_in, const int* in_sizes, int n_in,
                              void* d_out, int out_size, void* d_ws, size_t ws_size,
                              hipStream_t stream) {
    const float* x      = (const float*)d_in[0];
    const float* ln1_w  = (const float*)d_in[1];
    const float* ln1_b  = (const float*)d_in[2];
    const float* qkv_w  = (const float*)d_in[3];
    const float* proj_w = (const float*)d_in[4];
    const float* proj_b = (const float*)d_in[5];
    const float* ln2_w  = (const float*)d_in[6];
    const float* ln2_b  = (const float*)d_in[7];
    const float* fc1_w  = (const float*)d_in[8];
    const float* fc1_b  = (const float*)d_in[9];
    const float* fc2_w  = (const float*)d_in[10];
    const float* fc2_b  = (const float*)d_in[11];
    float* X = (float*)d_out;

    char* ws = (char*)d_ws;
    bf16* h_bf   = (bf16*)(ws);                       // 8 MB
    bf16* scr_bf = (bf16*)(ws + (size_t)(8  << 20));  // qkv 24 MB | gelu 32 MB
    bf16* vt_bf  = (bf16*)(ws + (size_t)(32 << 20));  // 8 MB
    bf16* o_bf   = (bf16*)(ws + (size_t)(40 << 20));  // 8 MB
    bf16* w_qkv  = (bf16*)(ws + (size_t)(48 << 20));
    bf16* w_proj = w_qkv  + (size_t)4 * 1536 * 512;
    bf16* w_fc1  = w_proj + (size_t)4 * 512 * 512;
    bf16* w_fc2  = w_fc1  + (size_t)4 * 2048 * 512;

    {
        int n;
        n = 4 * 1536 * 512; cvt_bf16_kernel<<<n / 1024, 256, 0, stream>>>(qkv_w,  w_qkv,  n);
        n = 4 * 512 * 512;  cvt_bf16_kernel<<<n / 1024, 256, 0, stream>>>(proj_w, w_proj, n);
        n = 4 * 2048 * 512; cvt_bf16_kernel<<<n / 1024, 256, 0, stream>>>(fc1_w,  w_fc1,  n);
        n = 4 * 512 * 2048; cvt_bf16_kernel<<<n / 1024, 256, 0, stream>>>(fc2_w,  w_fc2,  n);
    }

    for (int i = 0; i < 4; ++i) {
        const float* Xin = (i == 0) ? x : X;   // layer 0 reads the input directly
        ln_kernel<<<M_TOK / 4, 256, 0, stream>>>(Xin, ln1_w + i * 512, ln1_b + i * 512, h_bf);
        gemm128<0, 512><<<(M_TOK / 128) * (1536 / 128), 256, 0, stream>>>(
            h_bf, w_qkv + (size_t)i * 1536 * 512, nullptr, nullptr, scr_bf, 1536, vt_bf);
        attn_kernel<<<1024, 256, 0, stream>>>(scr_bf, vt_bf, o_bf);
        gemm_n64<512, 512, 1><<<dim3(8, 64), 256, 0, stream>>>(
            o_bf, w_proj + (size_t)i * 512 * 512, proj_b + i * 512, Xin, X);
        ln_kernel<<<M_TOK / 4, 256, 0, stream>>>(X, ln2_w + i * 512, ln2_b + i * 512, h_bf);
        gemm128<2, 512><<<(M_TOK / 128) * (2048 / 128), 256, 0, stream>>>(
            h_bf, w_fc1 + (size_t)i * 2048 * 512, fc1_b + i * 2048, nullptr, scr_bf, 2048, nullptr);
        gemm_n64<2048, 512, 1><<<dim3(8, 64), 256, 0, stream>>>(
            scr_bf, w_fc2 + (size_t)i * 512 * 2048, fc2_b + i * 512, X, X);
    }
}

// Round 16
// 706.630 us; speedup vs baseline: 1.0187x; 1.0187x over previous
//
#include <hip/hip_runtime.h>
#include <hip/hip_bf16.h>
#include <math.h>

#define NB 4
#define HEADS 8
#define DIM 512
#define MLP 2048
#define NT 2048
#define DH 64
#define M_TOK (NB*NT)

typedef __bf16 bf16;
typedef __bf16 bf16x2 __attribute__((ext_vector_type(2)));
typedef __bf16 bf16x4 __attribute__((ext_vector_type(4)));
typedef __bf16 bf16x8 __attribute__((ext_vector_type(8)));
typedef float f32x4 __attribute__((ext_vector_type(4)));

__device__ __forceinline__ void gl_lds16(const void* g, void* l) {
    __builtin_amdgcn_global_load_lds((const __attribute__((address_space(1))) unsigned int*)g,
                                     (__attribute__((address_space(3))) unsigned int*)l, 16, 0, 0);
}

#define BARRIER() do { __builtin_amdgcn_s_barrier(); asm volatile("" ::: "memory"); } while(0)
#define WAIT_VM4() asm volatile("s_waitcnt vmcnt(4)" ::: "memory")
#define WAIT_VM0() asm volatile("s_waitcnt vmcnt(0)" ::: "memory")

// tanh-form GELU: ~8 VALU instrs vs erff's ~20+; max |err| ~5e-4; exact at +-inf.
__device__ __forceinline__ float fast_gelu(float u) {
    float u2 = u * u;
    float y  = u * __builtin_fmaf(u2, 0.044715f, 1.0f);
    float e  = exp2f(y * 2.3021839f);          // exp(2*0.79788456*y)
    float r  = __builtin_amdgcn_rcpf(e + 1.0f);
    return u - u * r;                           // u * e/(e+1)
}

// ---------------- fused fp32 -> bf16 weight conversion (all 4 tensors, 1 launch) ----------------
// block ranges: qkv [0,3072), proj [3072,4096), fc1 [4096,8192), fc2 [8192,12288)
__global__ void cvt_all_kernel(const float* __restrict__ qkv_w, const float* __restrict__ proj_w,
                               const float* __restrict__ fc1_w, const float* __restrict__ fc2_w,
                               bf16* __restrict__ w_qkv, bf16* __restrict__ w_proj,
                               bf16* __restrict__ w_fc1, bf16* __restrict__ w_fc2) {
    int b = blockIdx.x;
    const float* src;
    bf16* dst;
    int base;
    if (b < 3072)      { src = qkv_w;  dst = w_qkv;  base = b; }
    else if (b < 4096) { src = proj_w; dst = w_proj; base = b - 3072; }
    else if (b < 8192) { src = fc1_w;  dst = w_fc1;  base = b - 4096; }
    else               { src = fc2_w;  dst = w_fc2;  base = b - 8192; }
    long i = ((long)base * 256 + threadIdx.x) * 4;
    float4 v = *(const float4*)(src + i);
    bf16x4 o;
    o[0] = (bf16)v.x; o[1] = (bf16)v.y; o[2] = (bf16)v.z; o[3] = (bf16)v.w;
    *(bf16x4*)(dst + i) = o;
}

// ---------------- LayerNorm (one wave per row of 512) ----------------
__global__ void ln_kernel(const float* __restrict__ X, const float* __restrict__ gam,
                          const float* __restrict__ bet, bf16* __restrict__ out) {
    int w = threadIdx.x >> 6, l = threadIdx.x & 63;
    long row = (long)blockIdx.x * 4 + w;
    const float* xp = X + row * DIM + l * 8;
    float4 a = *(const float4*)xp;
    float4 b = *(const float4*)(xp + 4);
    float s1 = a.x + a.y + a.z + a.w + b.x + b.y + b.z + b.w;
    float s2 = a.x*a.x + a.y*a.y + a.z*a.z + a.w*a.w + b.x*b.x + b.y*b.y + b.z*b.z + b.w*b.w;
#pragma unroll
    for (int off = 32; off; off >>= 1) { s1 += __shfl_xor(s1, off); s2 += __shfl_xor(s2, off); }
    float mean = s1 * (1.f / 512.f);
    float var  = s2 * (1.f / 512.f) - mean * mean;
    float rstd = rsqrtf(var + 1e-5f);
    float4 g0 = *(const float4*)(gam + l * 8), g1 = *(const float4*)(gam + l * 8 + 4);
    float4 b0 = *(const float4*)(bet + l * 8), b1 = *(const float4*)(bet + l * 8 + 4);
    bf16x8 o;
    o[0] = (bf16)((a.x - mean) * rstd * g0.x + b0.x);
    o[1] = (bf16)((a.y - mean) * rstd * g0.y + b0.y);
    o[2] = (bf16)((a.z - mean) * rstd * g0.z + b0.z);
    o[3] = (bf16)((a.w - mean) * rstd * g0.w + b0.w);
    o[4] = (bf16)((b.x - mean) * rstd * g1.x + b1.x);
    o[5] = (bf16)((b.y - mean) * rstd * g1.y + b1.y);
    o[6] = (bf16)((b.z - mean) * rstd * g1.z + b1.z);
    o[7] = (bf16)((b.w - mean) * rstd * g1.w + b1.w);
    *(bf16x8*)(out + row * DIM + l * 8) = o;
}

// ================= 128x128 8-phase GEMM (4 waves, BK=64, dbuf) — qkv / fc1 =================
#define G_LOADA(AF, B_, MQ) do { \
  _Pragma("unroll") for (int mi_ = 0; mi_ < 2; ++mi_) \
  _Pragma("unroll") for (int kk_ = 0; kk_ < 2; ++kk_) { \
    int row_ = wr * 64 + ((MQ) * 2 + mi_) * 16 + c; \
    AF[mi_][kk_] = *(const bf16x8*)&Abuf[B_][row_ * 64 + (((kk_ * 64 + g * 16) ^ sw) >> 1)]; \
  } } while (0)

#define G_LOADB(BF, B_, NQ) do { \
  _Pragma("unroll") for (int ni_ = 0; ni_ < 2; ++ni_) \
  _Pragma("unroll") for (int kk_ = 0; kk_ < 2; ++kk_) { \
    int row_ = wc * 64 + ((NQ) * 2 + ni_) * 16 + c; \
    BF[ni_][kk_] = *(const bf16x8*)&Bbuf[B_][row_ * 64 + (((kk_ * 64 + g * 16) ^ sw) >> 1)]; \
  } } while (0)

#define G_MFMA(AF, BF, MQ, NQ) do { \
  __builtin_amdgcn_s_setprio(1); \
  _Pragma("unroll") for (int mi_ = 0; mi_ < 2; ++mi_) \
  _Pragma("unroll") for (int ni_ = 0; ni_ < 2; ++ni_) \
  _Pragma("unroll") for (int kk_ = 0; kk_ < 2; ++kk_) \
    acc[(MQ)*2+mi_][(NQ)*2+ni_] = __builtin_amdgcn_mfma_f32_16x16x32_bf16( \
        AF[mi_][kk_], BF[ni_][kk_], acc[(MQ)*2+mi_][(NQ)*2+ni_], 0, 0, 0); \
  __builtin_amdgcn_s_setprio(0); \
} while (0)

#define G_STAGE_A(J_, H_) do { int j_ = (J_); if (j_ < nkt) { \
  bf16* db_ = Abuf[j_ & 1]; const bf16* sb_ = Aptr + (size_t)j_ * 64 + coloff; \
  _Pragma("unroll") for (int q_ = 0; q_ < 2; ++q_) { \
    int rw_ = q_ * 64 + (H_) * 32 + (w << 3); \
    gl_lds16(sb_ + (size_t)(arow0 + rw_ + lr) * KN, db_ + rw_ * 64); \
  } } } while (0)

#define G_STAGE_B(J_, H_) do { int j_ = (J_); if (j_ < nkt) { \
  bf16* db_ = Bbuf[j_ & 1]; const bf16* sb_ = Wptr + (size_t)j_ * 64 + coloff; \
  _Pragma("unroll") for (int q_ = 0; q_ < 2; ++q_) { \
    int rw_ = q_ * 64 + (H_) * 32 + (w << 3); \
    gl_lds16(sb_ + (size_t)(bcol0 + rw_ + lr) * KN, db_ + rw_ * 64); \
  } } } while (0)

// EPI 0: QKV scatter (Q pre-scaled by 0.125*log2e; V transposed to vt)
// EPI 2: +bias fast-GELU -> bf16 (fc1)
template<int EPI, int KN>
__global__ __launch_bounds__(256, 2) void gemm128(const bf16* __restrict__ Aptr,
                                                  const bf16* __restrict__ Wptr,
                                                  const float* __restrict__ bias,
                                                  const float* __restrict__ resid,
                                                  void* outp, int N, bf16* __restrict__ vtout) {
    __shared__ bf16 Abuf[2][128 * 64];
    __shared__ bf16 Bbuf[2][128 * 64];
    const int t = threadIdx.x, w = t >> 6, l = t & 63;
    const int wr = w >> 1, wc = w & 1, g = l >> 4, c = l & 15;
    const int sw = (c & 7) << 4;
    const int lr = l >> 3;
    const int coloff = ((l & 7) ^ lr) << 3;

    int nwg = gridDim.x, bid = blockIdx.x;
    int q8 = nwg >> 3, r8 = nwg & 7;
    int xcd = bid & 7, rank = bid >> 3;
    int swz = (xcd < r8) ? xcd * (q8 + 1) + rank : r8 * (q8 + 1) + (xcd - r8) * q8 + rank;
    int tiles_n = N >> 7;
    long arow0 = (long)(swz / tiles_n) * 128;
    long bcol0 = (long)(swz % tiles_n) * 128;

    const int nkt = KN / 64;
    const int niter = nkt / 2;
    f32x4 acc[4][4] = {};
    bf16x8 af[2][2], bn0[2][2], bn1[2][2];

    G_STAGE_A(0, 0); G_STAGE_B(0, 0); G_STAGE_A(0, 1); G_STAGE_B(0, 1);
    G_STAGE_A(1, 0); G_STAGE_B(1, 0);

#pragma unroll 1
    for (int tt = 0; tt < niter; ++tt) {
        const int J0 = 2 * tt, J1 = 2 * tt + 1;
        const bool last = (tt == niter - 1);
        WAIT_VM4(); BARRIER();
        G_LOADA(af, 0, 0); G_LOADB(bn0, 0, 0);
        G_STAGE_A(J0 + 1, 1);
        G_MFMA(af, bn0, 0, 0);
        BARRIER();
        G_LOADB(bn1, 0, 1);
        G_STAGE_B(J0 + 1, 1);
        G_MFMA(af, bn1, 0, 1);
        BARRIER();
        G_LOADA(af, 0, 1);
        G_STAGE_A(J0 + 2, 0);
        G_MFMA(af, bn0, 1, 0);
        BARRIER();
        G_STAGE_B(J0 + 2, 0);
        G_MFMA(af, bn1, 1, 1);
        BARRIER();
        if (last) { WAIT_VM0(); } else { WAIT_VM4(); }
        BARRIER();
        G_LOADA(af, 1, 0); G_LOADB(bn0, 1, 0);
        G_STAGE_A(J1 + 1, 1);
        G_MFMA(af, bn0, 0, 0);
        BARRIER();
        G_LOADB(bn1, 1, 1);
        G_STAGE_B(J1 + 1, 1);
        G_MFMA(af, bn1, 0, 1);
        BARRIER();
        G_LOADA(af, 1, 1);
        G_STAGE_A(J1 + 2, 0);
        G_MFMA(af, bn0, 1, 0);
        BARRIER();
        G_STAGE_B(J1 + 2, 0);
        G_MFMA(af, bn1, 1, 1);
        BARRIER();
    }

    if constexpr (EPI == 0) {
        const int s = (int)(bcol0 >> 9);
        const float qscale = 0.18033688011112042f;   // 0.125 * log2(e)
        if (s == 2) {
#pragma unroll
            for (int m = 0; m < 4; ++m)
#pragma unroll
                for (int n = 0; n < 4; ++n) {
                    int col = (int)(bcol0 + wc * 64 + n * 16 + c);
                    int d = col & 63, hh = (col >> 6) & 7;
                    long row = arow0 + wr * 64 + m * 16 + g * 4;
                    int bb = (int)(row >> 11), nn = (int)(row & 2047);
                    bf16x4 o4;
#pragma unroll
                    for (int r = 0; r < 4; ++r) o4[r] = (bf16)acc[m][n][r];
                    *(bf16x4*)(vtout + ((long)(bb * 8 + hh) * 64 + d) * 2048 + nn) = o4;
                }
        } else {
            const float sc = (s == 0) ? qscale : 1.0f;
#pragma unroll
            for (int m = 0; m < 4; ++m)
#pragma unroll
                for (int n = 0; n < 4; ++n) {
                    int col = (int)(bcol0 + wc * 64 + n * 16 + c);
                    int hh = (col >> 6) & 7, d = col & 63;
                    long row = arow0 + wr * 64 + m * 16 + g * 4;
#pragma unroll
                    for (int r = 0; r < 4; ++r) {
                        long rr = row + r;
                        int bb = (int)(rr >> 11), nn = (int)(rr & 2047);
                        ((bf16*)outp)[(((long)(s * NB + bb) * HEADS + hh) * NT + nn) * DH + d] =
                            (bf16)(acc[m][n][r] * sc);
                    }
                }
        }
    } else {
#pragma unroll
        for (int m = 0; m < 4; ++m)
#pragma unroll
            for (int n = 0; n < 4; ++n) {
                long row = arow0 + wr * 64 + m * 16 + g * 4;
                long col = bcol0 + wc * 64 + n * 16 + c;
#pragma unroll
                for (int r = 0; r < 4; ++r) {
                    long rr = row + r;
                    float u = acc[m][n][r] + bias[col];
                    ((bf16*)outp)[rr * N + col] = (bf16)fast_gelu(u);
                }
            }
    }
}

// ======== 128x64-tile 2-phase GEMM (m97 structure), N=512 out (proj / fc2) ========
template<int KN, int NOUT, int EPI>
__global__ __launch_bounds__(256, 2) void gemm_n64(const bf16* __restrict__ A,
                                                   const bf16* __restrict__ W,
                                                   const float* __restrict__ bias,
                                                   const float* __restrict__ resid,
                                                   void* __restrict__ outp) {
    __shared__ bf16 As[128 * 64];
    __shared__ bf16 Bs[64 * 64];
    const int t = threadIdx.x, w = t >> 6, l = t & 63;
    const int wr = w >> 1, wc = w & 1, g = l >> 4, c = l & 15;
    const long arow0 = (long)blockIdx.y * 128;
    const long bcol0 = (long)blockIdx.x * 64;
    f32x4 acc[4][2] = {};
    const int lrow = l >> 3, lcol = (l & 7) * 8;
    const bf16* Ab = A + (arow0 + lrow) * (long)KN + lcol;
    const bf16* Wb = W + (bcol0 + lrow) * (long)KN + lcol;
    for (int k0 = 0; k0 < KN; k0 += 64) {
#pragma unroll
        for (int q = 0; q < 4; ++q)
            gl_lds16(Ab + (long)(w * 4 + q) * 8 * KN + k0, &As[(w * 4 + q) * 512]);
#pragma unroll
        for (int q = 0; q < 2; ++q)
            gl_lds16(Wb + (long)(w * 2 + q) * 8 * KN + k0, &Bs[(w * 2 + q) * 512]);
        __syncthreads();
#pragma unroll
        for (int kk = 0; kk < 2; ++kk) {
            bf16x8 afv[4], bfr[2];
#pragma unroll
            for (int m = 0; m < 4; ++m)
                afv[m] = *(const bf16x8*)&As[(wr * 64 + m * 16 + c) * 64 + kk * 32 + g * 8];
#pragma unroll
            for (int n = 0; n < 2; ++n)
                bfr[n] = *(const bf16x8*)&Bs[(wc * 32 + n * 16 + c) * 64 + kk * 32 + g * 8];
#pragma unroll
            for (int m = 0; m < 4; ++m)
#pragma unroll
                for (int n = 0; n < 2; ++n)
                    acc[m][n] = __builtin_amdgcn_mfma_f32_16x16x32_bf16(afv[m], bfr[n], acc[m][n], 0, 0, 0);
        }
        __syncthreads();
    }
#pragma unroll
    for (int m = 0; m < 4; ++m)
#pragma unroll
        for (int n = 0; n < 2; ++n) {
            long row = arow0 + wr * 64 + m * 16 + g * 4;
            long col = bcol0 + wc * 32 + n * 16 + c;
#pragma unroll
            for (int r = 0; r < 4; ++r) {
                long rr = row + r;
                float v = acc[m][n][r] + bias[col];
                if constexpr (EPI == 1) {
                    ((float*)outp)[rr * NOUT + col] = v + resid[rr * NOUT + col];
                } else {
                    ((bf16*)outp)[rr * NOUT + col] = (bf16)fast_gelu(v);
                }
            }
        }
}

// ---------------- Flash attention v9b (measured best): cross-tile pipeline, st ping-pong ----------------
#define NKT (NT / 64)

#define ATT_STAGE(J_, B_) do { \
    const bf16* ks_ = kbase + (size_t)(J_) * (64 * DH); \
    const bf16* vs_ = vbase + (J_) * 64; \
    gl_lds16(ks_,           &Ks[B_][(w * 8) * 64]); \
    gl_lds16(ks_ + 32 * DH, &Ks[B_][(32 + w * 8) * 64]); \
    gl_lds16(vs_,           &Vs[B_][(w * 8) * 64]); \
    gl_lds16(vs_ + 32 * NT, &Vs[B_][(32 + w * 8) * 64]); \
} while (0)

#define ATT_QK(B_, ST) do { \
    bf16x8 kf_[4][2]; \
    _Pragma("unroll") for (int kc = 0; kc < 4; ++kc) \
    _Pragma("unroll") for (int kk = 0; kk < 2; ++kk) \
        kf_[kc][kk] = *(const bf16x8*)&Ks[B_][(kc * 16 + c) * 64 + (((kk * 64 + g * 16) ^ xr) >> 1)]; \
    _Pragma("unroll") for (int kc = 0; kc < 4; ++kc) \
    _Pragma("unroll") for (int kk = 0; kk < 2; ++kk) \
        ST[kc] = __builtin_amdgcn_mfma_f32_16x16x32_bf16(kf_[kc][kk], qf[kk], ST[kc], 0, 0, 0); \
} while (0)

#define ATT_BODY(BUF, KT, SIN, SOUT) do { \
    bf16x8 vf[4][2]; \
    _Pragma("unroll") for (int dc = 0; dc < 4; ++dc) \
    _Pragma("unroll") for (int ks = 0; ks < 2; ++ks) \
        vf[dc][ks] = *(const bf16x8*)((const char*)&Vs[BUF][0] + (dc * 16 + c) * 128 + ((ks * 64 + g * 16) ^ xr)); \
    bf16x8 pf[2]; \
    _Pragma("unroll") for (int a = 0; a < 4; ++a) \
    _Pragma("unroll") for (int r = 0; r < 4; ++r) \
        pf[a >> 1][(a & 1) * 4 + r] = (bf16)exp2f(SIN[a][r]); \
    __syncthreads(); \
    if ((KT) + 2 < NKT) ATT_STAGE((KT) + 2, BUF); \
    _Pragma("unroll") for (int kc = 0; kc < 4; ++kc) SOUT[kc] = z4; \
    __builtin_amdgcn_s_setprio(1); \
    if ((KT) + 1 < NKT) ATT_QK((BUF) ^ 1, SOUT); \
    _Pragma("unroll") for (int ks = 0; ks < 2; ++ks) \
        sacc = __builtin_amdgcn_mfma_f32_16x16x32_bf16(ones8, pf[ks], sacc, 0, 0, 0); \
    _Pragma("unroll") for (int dc = 0; dc < 4; ++dc) \
    _Pragma("unroll") for (int ks = 0; ks < 2; ++ks) \
        oacc[dc] = __builtin_amdgcn_mfma_f32_16x16x32_bf16(vf[dc][ks], pf[ks], oacc[dc], 0, 0, 0); \
    __builtin_amdgcn_s_setprio(0); \
} while (0)

__global__ __launch_bounds__(256, 4) void attn_kernel(const bf16* __restrict__ qkv,
                                                      const bf16* __restrict__ vt,
                                                      bf16* __restrict__ O) {
    __shared__ bf16 Ks[2][64 * 64];
    __shared__ bf16 Vs[2][64 * 64];
    const int t = threadIdx.x, w = t >> 6, l = t & 63;
    const int g = l >> 4, c = l & 15;
    const int wg = blockIdx.x;
    const int xcd = wg & 7, rank = wg >> 3;
    const int bh = xcd + 8 * (rank >> 5);
    const int qt = rank & 31;
    const bf16* Qb = qkv + (long)bh * (NT * DH);
    const bf16* Kb = Qb + (long)(NB * HEADS) * (NT * DH);
    const bf16* Vtb = vt + (long)bh * (DH * NT);
    const int q0 = qt * 64 + w * 16;
    const int lr = l >> 3, lc = l & 7;
    const int sch = ((lc ^ lr) & 7) * 8;
    const int xr = (c & 7) << 4;

    const bf16* kbase = Kb + (long)(w * 8 + lr) * DH + sch;
    const bf16* vbase = Vtb + (long)(w * 8 + lr) * NT + sch;

    bf16x8 qf[2];
#pragma unroll
    for (int kk = 0; kk < 2; ++kk)
        qf[kk] = *(const bf16x8*)(Qb + (long)(q0 + c) * DH + kk * 32 + g * 8);

    bf16x8 ones8;
#pragma unroll
    for (int j = 0; j < 8; ++j) ones8[j] = (bf16)1.0f;
    const f32x4 z4 = {};

    f32x4 oacc[4] = {};
    f32x4 sacc = {};
    f32x4 st0[4] = {}, st1[4];

    ATT_STAGE(0, 0);
    ATT_STAGE(1, 1);
    __syncthreads();
    ATT_QK(0, st0);

#pragma unroll 1
    for (int kt2 = 0; kt2 < NKT / 2; ++kt2) {
        ATT_BODY(0, kt2 * 2,     st0, st1);
        ATT_BODY(1, kt2 * 2 + 1, st1, st0);
    }

    float inv = 1.f / sacc[0];

    char* ol = (char*)&Ks[0][0] + w * 2048;
#pragma unroll
    for (int dc = 0; dc < 4; ++dc) {
        bf16x4 o4;
#pragma unroll
        for (int r = 0; r < 4; ++r) o4[r] = (bf16)(oacc[dc][r] * inv);
        *(bf16x4*)(ol + c * 128 + ((dc * 32 + g * 8) ^ xr)) = o4;
    }
    __builtin_amdgcn_s_waitcnt(0);  // lgkmcnt(0): wave-private region
    const int orow = l >> 2, oc = (l & 3) * 16;
    const int bb = bh >> 3, hh = bh & 7;
    long tok = (long)bb * NT + q0 + orow;
    bf16* og = O + tok * DIM + hh * 64 + oc;
    const int xr2 = (orow & 7) << 4;
    bf16x8 v0 = *(const bf16x8*)(ol + orow * 128 + ((oc * 2) ^ xr2));
    bf16x8 v1 = *(const bf16x8*)(ol + orow * 128 + ((oc * 2 + 16) ^ xr2));
    *(bf16x8*)og = v0;
    *(bf16x8*)(og + 8) = v1;
}

extern "C" void kernel_launch(void* const* d_in, const int* in_sizes, int n_in,
                              void* d_out, int out_size, void* d_ws, size_t ws_size,
                              hipStream_t stream) {
    const float* x      = (const float*)d_in[0];
    const float* ln1_w  = (const float*)d_in[1];
    const float* ln1_b  = (const float*)d_in[2];
    const float* qkv_w  = (const float*)d_in[3];
    const float* proj_w = (const float*)d_in[4];
    const float* proj_b = (const float*)d_in[5];
    const float* ln2_w  = (const float*)d_in[6];
    const float* ln2_b  = (const float*)d_in[7];
    const float* fc1_w  = (const float*)d_in[8];
    const float* fc1_b  = (const float*)d_in[9];
    const float* fc2_w  = (const float*)d_in[10];
    const float* fc2_b  = (const float*)d_in[11];
    float* X = (float*)d_out;

    char* ws = (char*)d_ws;
    bf16* h_bf   = (bf16*)(ws);                       // 8 MB
    bf16* scr_bf = (bf16*)(ws + (size_t)(8  << 20));  // qkv 24 MB | gelu 32 MB
    bf16* vt_bf  = (bf16*)(ws + (size_t)(32 << 20));  // 8 MB
    bf16* o_bf   = (bf16*)(ws + (size_t)(40 << 20));  // 8 MB
    bf16* w_qkv  = (bf16*)(ws + (size_t)(48 << 20));
    bf16* w_proj = w_qkv  + (size_t)4 * 1536 * 512;
    bf16* w_fc1  = w_proj + (size_t)4 * 512 * 512;
    bf16* w_fc2  = w_fc1  + (size_t)4 * 2048 * 512;

    // one fused weight-conversion launch (12288 blocks x 256 threads, 4 el/thread)
    cvt_all_kernel<<<12288, 256, 0, stream>>>(qkv_w, proj_w, fc1_w, fc2_w,
                                              w_qkv, w_proj, w_fc1, w_fc2);

    for (int i = 0; i < 4; ++i) {
        const float* Xin = (i == 0) ? x : X;   // layer 0 reads the input directly
        ln_kernel<<<M_TOK / 4, 256, 0, stream>>>(Xin, ln1_w + i * 512, ln1_b + i * 512, h_bf);
        gemm128<0, 512><<<(M_TOK / 128) * (1536 / 128), 256, 0, stream>>>(
            h_bf, w_qkv + (size_t)i * 1536 * 512, nullptr, nullptr, scr_bf, 1536, vt_bf);
        attn_kernel<<<1024, 256, 0, stream>>>(scr_bf, vt_bf, o_bf);
        gemm_n64<512, 512, 1><<<dim3(8, 64), 256, 0, stream>>>(
            o_bf, w_proj + (size_t)i * 512 * 512, proj_b + i * 512, Xin, X);
        ln_kernel<<<M_TOK / 4, 256, 0, stream>>>(X, ln2_w + i * 512, ln2_b + i * 512, h_bf);
        gemm128<2, 512><<<(M_TOK / 128) * (2048 / 128), 256, 0, stream>>>(
            h_bf, w_fc1 + (size_t)i * 2048 * 512, fc1_b + i * 2048, nullptr, scr_bf, 2048, nullptr);
        gemm_n64<2048, 512, 1><<<dim3(8, 64), 256, 0, stream>>>(
            scr_bf, w_fc2 + (size_t)i * 512 * 2048, fc2_b + i * 512, X, X);
    }
}

// Round 17
// 698.792 us; speedup vs baseline: 1.0301x; 1.0112x over previous
//
#include <hip/hip_runtime.h>
#include <hip/hip_bf16.h>
#include <math.h>

#define NB 4
#define HEADS 8
#define DIM 512
#define MLP 2048
#define NT 2048
#define DH 64
#define M_TOK (NB*NT)

typedef __bf16 bf16;
typedef __bf16 bf16x2 __attribute__((ext_vector_type(2)));
typedef __bf16 bf16x4 __attribute__((ext_vector_type(4)));
typedef __bf16 bf16x8 __attribute__((ext_vector_type(8)));
typedef float f32x4 __attribute__((ext_vector_type(4)));

__device__ __forceinline__ void gl_lds16(const void* g, void* l) {
    __builtin_amdgcn_global_load_lds((const __attribute__((address_space(1))) unsigned int*)g,
                                     (__attribute__((address_space(3))) unsigned int*)l, 16, 0, 0);
}

#define BARRIER() do { __builtin_amdgcn_s_barrier(); asm volatile("" ::: "memory"); } while(0)
#define WAIT_VM4() asm volatile("s_waitcnt vmcnt(4)" ::: "memory")
#define WAIT_VM0() asm volatile("s_waitcnt vmcnt(0)" ::: "memory")

// tanh-form GELU: ~8 VALU instrs vs erff's ~20+; max |err| ~5e-4; exact at +-inf.
__device__ __forceinline__ float fast_gelu(float u) {
    float u2 = u * u;
    float y  = u * __builtin_fmaf(u2, 0.044715f, 1.0f);
    float e  = exp2f(y * 2.3021839f);          // exp(2*0.79788456*y)
    float r  = __builtin_amdgcn_rcpf(e + 1.0f);
    return u - u * r;                           // u * e/(e+1)
}

// ---------------- fused fp32 -> bf16 weight conversion (all 4 tensors, 1 launch) ----------------
__global__ void cvt_all_kernel(const float* __restrict__ qkv_w, const float* __restrict__ proj_w,
                               const float* __restrict__ fc1_w, const float* __restrict__ fc2_w,
                               bf16* __restrict__ w_qkv, bf16* __restrict__ w_proj,
                               bf16* __restrict__ w_fc1, bf16* __restrict__ w_fc2) {
    int b = blockIdx.x;
    const float* src;
    bf16* dst;
    int base;
    if (b < 3072)      { src = qkv_w;  dst = w_qkv;  base = b; }
    else if (b < 4096) { src = proj_w; dst = w_proj; base = b - 3072; }
    else if (b < 8192) { src = fc1_w;  dst = w_fc1;  base = b - 4096; }
    else               { src = fc2_w;  dst = w_fc2;  base = b - 8192; }
    long i = ((long)base * 256 + threadIdx.x) * 4;
    float4 v = *(const float4*)(src + i);
    bf16x4 o;
    o[0] = (bf16)v.x; o[1] = (bf16)v.y; o[2] = (bf16)v.z; o[3] = (bf16)v.w;
    *(bf16x4*)(dst + i) = o;
}

// ---------------- LayerNorm (one wave per row of 512); input fp32 or bf16 ----------------
template<bool INF32>
__global__ void ln_kernel(const void* __restrict__ Xv, const float* __restrict__ gam,
                          const float* __restrict__ bet, bf16* __restrict__ out) {
    int w = threadIdx.x >> 6, l = threadIdx.x & 63;
    long row = (long)blockIdx.x * 4 + w;
    float xv[8];
    if constexpr (INF32) {
        const float* xp = (const float*)Xv + row * DIM + l * 8;
        float4 a = *(const float4*)xp;
        float4 b = *(const float4*)(xp + 4);
        xv[0] = a.x; xv[1] = a.y; xv[2] = a.z; xv[3] = a.w;
        xv[4] = b.x; xv[5] = b.y; xv[6] = b.z; xv[7] = b.w;
    } else {
        bf16x8 v = *(const bf16x8*)((const bf16*)Xv + row * DIM + l * 8);
#pragma unroll
        for (int j = 0; j < 8; ++j) xv[j] = (float)v[j];
    }
    float s1 = 0.f, s2 = 0.f;
#pragma unroll
    for (int j = 0; j < 8; ++j) { s1 += xv[j]; s2 += xv[j] * xv[j]; }
#pragma unroll
    for (int off = 32; off; off >>= 1) { s1 += __shfl_xor(s1, off); s2 += __shfl_xor(s2, off); }
    float mean = s1 * (1.f / 512.f);
    float var  = s2 * (1.f / 512.f) - mean * mean;
    float rstd = rsqrtf(var + 1e-5f);
    float ga[8], be[8];
    {
        float4 g0 = *(const float4*)(gam + l * 8), g1 = *(const float4*)(gam + l * 8 + 4);
        float4 b0 = *(const float4*)(bet + l * 8), b1 = *(const float4*)(bet + l * 8 + 4);
        ga[0] = g0.x; ga[1] = g0.y; ga[2] = g0.z; ga[3] = g0.w;
        ga[4] = g1.x; ga[5] = g1.y; ga[6] = g1.z; ga[7] = g1.w;
        be[0] = b0.x; be[1] = b0.y; be[2] = b0.z; be[3] = b0.w;
        be[4] = b1.x; be[5] = b1.y; be[6] = b1.z; be[7] = b1.w;
    }
    bf16x8 o;
#pragma unroll
    for (int j = 0; j < 8; ++j) o[j] = (bf16)((xv[j] - mean) * rstd * ga[j] + be[j]);
    *(bf16x8*)(out + row * DIM + l * 8) = o;
}

// ================= 128x128 8-phase GEMM (4 waves, BK=64, dbuf) — qkv / fc1 =================
#define G_LOADA(AF, B_, MQ) do { \
  _Pragma("unroll") for (int mi_ = 0; mi_ < 2; ++mi_) \
  _Pragma("unroll") for (int kk_ = 0; kk_ < 2; ++kk_) { \
    int row_ = wr * 64 + ((MQ) * 2 + mi_) * 16 + c; \
    AF[mi_][kk_] = *(const bf16x8*)&Abuf[B_][row_ * 64 + (((kk_ * 64 + g * 16) ^ sw) >> 1)]; \
  } } while (0)

#define G_LOADB(BF, B_, NQ) do { \
  _Pragma("unroll") for (int ni_ = 0; ni_ < 2; ++ni_) \
  _Pragma("unroll") for (int kk_ = 0; kk_ < 2; ++kk_) { \
    int row_ = wc * 64 + ((NQ) * 2 + ni_) * 16 + c; \
    BF[ni_][kk_] = *(const bf16x8*)&Bbuf[B_][row_ * 64 + (((kk_ * 64 + g * 16) ^ sw) >> 1)]; \
  } } while (0)

#define G_MFMA(AF, BF, MQ, NQ) do { \
  __builtin_amdgcn_s_setprio(1); \
  _Pragma("unroll") for (int mi_ = 0; mi_ < 2; ++mi_) \
  _Pragma("unroll") for (int ni_ = 0; ni_ < 2; ++ni_) \
  _Pragma("unroll") for (int kk_ = 0; kk_ < 2; ++kk_) \
    acc[(MQ)*2+mi_][(NQ)*2+ni_] = __builtin_amdgcn_mfma_f32_16x16x32_bf16( \
        AF[mi_][kk_], BF[ni_][kk_], acc[(MQ)*2+mi_][(NQ)*2+ni_], 0, 0, 0); \
  __builtin_amdgcn_s_setprio(0); \
} while (0)

#define G_STAGE_A(J_, H_) do { int j_ = (J_); if (j_ < nkt) { \
  bf16* db_ = Abuf[j_ & 1]; const bf16* sb_ = Aptr + (size_t)j_ * 64 + coloff; \
  _Pragma("unroll") for (int q_ = 0; q_ < 2; ++q_) { \
    int rw_ = q_ * 64 + (H_) * 32 + (w << 3); \
    gl_lds16(sb_ + (size_t)(arow0 + rw_ + lr) * KN, db_ + rw_ * 64); \
  } } } while (0)

#define G_STAGE_B(J_, H_) do { int j_ = (J_); if (j_ < nkt) { \
  bf16* db_ = Bbuf[j_ & 1]; const bf16* sb_ = Wptr + (size_t)j_ * 64 + coloff; \
  _Pragma("unroll") for (int q_ = 0; q_ < 2; ++q_) { \
    int rw_ = q_ * 64 + (H_) * 32 + (w << 3); \
    gl_lds16(sb_ + (size_t)(bcol0 + rw_ + lr) * KN, db_ + rw_ * 64); \
  } } } while (0)

// EPI 0: QKV scatter (Q pre-scaled by 0.125*log2e; V transposed to vt)
// EPI 2: +bias fast-GELU -> bf16 (fc1)
template<int EPI, int KN>
__global__ __launch_bounds__(256, 2) void gemm128(const bf16* __restrict__ Aptr,
                                                  const bf16* __restrict__ Wptr,
                                                  const float* __restrict__ bias,
                                                  const float* __restrict__ resid,
                                                  void* outp, int N, bf16* __restrict__ vtout) {
    __shared__ bf16 Abuf[2][128 * 64];
    __shared__ bf16 Bbuf[2][128 * 64];
    const int t = threadIdx.x, w = t >> 6, l = t & 63;
    const int wr = w >> 1, wc = w & 1, g = l >> 4, c = l & 15;
    const int sw = (c & 7) << 4;
    const int lr = l >> 3;
    const int coloff = ((l & 7) ^ lr) << 3;

    int nwg = gridDim.x, bid = blockIdx.x;
    int q8 = nwg >> 3, r8 = nwg & 7;
    int xcd = bid & 7, rank = bid >> 3;
    int swz = (xcd < r8) ? xcd * (q8 + 1) + rank : r8 * (q8 + 1) + (xcd - r8) * q8 + rank;
    int tiles_n = N >> 7;
    long arow0 = (long)(swz / tiles_n) * 128;
    long bcol0 = (long)(swz % tiles_n) * 128;

    const int nkt = KN / 64;
    const int niter = nkt / 2;
    f32x4 acc[4][4] = {};
    bf16x8 af[2][2], bn0[2][2], bn1[2][2];

    G_STAGE_A(0, 0); G_STAGE_B(0, 0); G_STAGE_A(0, 1); G_STAGE_B(0, 1);
    G_STAGE_A(1, 0); G_STAGE_B(1, 0);

#pragma unroll 1
    for (int tt = 0; tt < niter; ++tt) {
        const int J0 = 2 * tt, J1 = 2 * tt + 1;
        const bool last = (tt == niter - 1);
        WAIT_VM4(); BARRIER();
        G_LOADA(af, 0, 0); G_LOADB(bn0, 0, 0);
        G_STAGE_A(J0 + 1, 1);
        G_MFMA(af, bn0, 0, 0);
        BARRIER();
        G_LOADB(bn1, 0, 1);
        G_STAGE_B(J0 + 1, 1);
        G_MFMA(af, bn1, 0, 1);
        BARRIER();
        G_LOADA(af, 0, 1);
        G_STAGE_A(J0 + 2, 0);
        G_MFMA(af, bn0, 1, 0);
        BARRIER();
        G_STAGE_B(J0 + 2, 0);
        G_MFMA(af, bn1, 1, 1);
        BARRIER();
        if (last) { WAIT_VM0(); } else { WAIT_VM4(); }
        BARRIER();
        G_LOADA(af, 1, 0); G_LOADB(bn0, 1, 0);
        G_STAGE_A(J1 + 1, 1);
        G_MFMA(af, bn0, 0, 0);
        BARRIER();
        G_LOADB(bn1, 1, 1);
        G_STAGE_B(J1 + 1, 1);
        G_MFMA(af, bn1, 0, 1);
        BARRIER();
        G_LOADA(af, 1, 1);
        G_STAGE_A(J1 + 2, 0);
        G_MFMA(af, bn0, 1, 0);
        BARRIER();
        G_STAGE_B(J1 + 2, 0);
        G_MFMA(af, bn1, 1, 1);
        BARRIER();
    }

    if constexpr (EPI == 0) {
        const int s = (int)(bcol0 >> 9);
        const float qscale = 0.18033688011112042f;   // 0.125 * log2(e)
        if (s == 2) {
#pragma unroll
            for (int m = 0; m < 4; ++m)
#pragma unroll
                for (int n = 0; n < 4; ++n) {
                    int col = (int)(bcol0 + wc * 64 + n * 16 + c);
                    int d = col & 63, hh = (col >> 6) & 7;
                    long row = arow0 + wr * 64 + m * 16 + g * 4;
                    int bb = (int)(row >> 11), nn = (int)(row & 2047);
                    bf16x4 o4;
#pragma unroll
                    for (int r = 0; r < 4; ++r) o4[r] = (bf16)acc[m][n][r];
                    *(bf16x4*)(vtout + ((long)(bb * 8 + hh) * 64 + d) * 2048 + nn) = o4;
                }
        } else {
            const float sc = (s == 0) ? qscale : 1.0f;
#pragma unroll
            for (int m = 0; m < 4; ++m)
#pragma unroll
                for (int n = 0; n < 4; ++n) {
                    int col = (int)(bcol0 + wc * 64 + n * 16 + c);
                    int hh = (col >> 6) & 7, d = col & 63;
                    long row = arow0 + wr * 64 + m * 16 + g * 4;
#pragma unroll
                    for (int r = 0; r < 4; ++r) {
                        long rr = row + r;
                        int bb = (int)(rr >> 11), nn = (int)(rr & 2047);
                        ((bf16*)outp)[(((long)(s * NB + bb) * HEADS + hh) * NT + nn) * DH + d] =
                            (bf16)(acc[m][n][r] * sc);
                    }
                }
        }
    } else {
#pragma unroll
        for (int m = 0; m < 4; ++m)
#pragma unroll
            for (int n = 0; n < 4; ++n) {
                long row = arow0 + wr * 64 + m * 16 + g * 4;
                long col = bcol0 + wc * 64 + n * 16 + c;
#pragma unroll
                for (int r = 0; r < 4; ++r) {
                    long rr = row + r;
                    float u = acc[m][n][r] + bias[col];
                    ((bf16*)outp)[rr * N + col] = (bf16)fast_gelu(u);
                }
            }
    }
}

// ======== 128x64-tile 2-phase GEMM (m97 structure), N=512 out (proj / fc2) ========
// RESF32: residual read fp32 (layer-0 proj reads x); else bf16 X stream.
// OUTF32: write fp32 (layer-3 fc2 -> d_out); else bf16 X stream.
template<int KN, bool RESF32, bool OUTF32>
__global__ __launch_bounds__(256, 2) void gemm_n64(const bf16* __restrict__ A,
                                                   const bf16* __restrict__ W,
                                                   const float* __restrict__ bias,
                                                   const void* __restrict__ residv,
                                                   void* __restrict__ outp) {
    __shared__ bf16 As[128 * 64];
    __shared__ bf16 Bs[64 * 64];
    const int t = threadIdx.x, w = t >> 6, l = t & 63;
    const int wr = w >> 1, wc = w & 1, g = l >> 4, c = l & 15;
    const long arow0 = (long)blockIdx.y * 128;
    const long bcol0 = (long)blockIdx.x * 64;
    f32x4 acc[4][2] = {};
    const int lrow = l >> 3, lcol = (l & 7) * 8;
    const bf16* Ab = A + (arow0 + lrow) * (long)KN + lcol;
    const bf16* Wb = W + (bcol0 + lrow) * (long)KN + lcol;
    for (int k0 = 0; k0 < KN; k0 += 64) {
#pragma unroll
        for (int q = 0; q < 4; ++q)
            gl_lds16(Ab + (long)(w * 4 + q) * 8 * KN + k0, &As[(w * 4 + q) * 512]);
#pragma unroll
        for (int q = 0; q < 2; ++q)
            gl_lds16(Wb + (long)(w * 2 + q) * 8 * KN + k0, &Bs[(w * 2 + q) * 512]);
        __syncthreads();
#pragma unroll
        for (int kk = 0; kk < 2; ++kk) {
            bf16x8 afv[4], bfr[2];
#pragma unroll
            for (int m = 0; m < 4; ++m)
                afv[m] = *(const bf16x8*)&As[(wr * 64 + m * 16 + c) * 64 + kk * 32 + g * 8];
#pragma unroll
            for (int n = 0; n < 2; ++n)
                bfr[n] = *(const bf16x8*)&Bs[(wc * 32 + n * 16 + c) * 64 + kk * 32 + g * 8];
#pragma unroll
            for (int m = 0; m < 4; ++m)
#pragma unroll
                for (int n = 0; n < 2; ++n)
                    acc[m][n] = __builtin_amdgcn_mfma_f32_16x16x32_bf16(afv[m], bfr[n], acc[m][n], 0, 0, 0);
        }
        __syncthreads();
    }
#pragma unroll
    for (int m = 0; m < 4; ++m)
#pragma unroll
        for (int n = 0; n < 2; ++n) {
            long row = arow0 + wr * 64 + m * 16 + g * 4;
            long col = bcol0 + wc * 32 + n * 16 + c;
#pragma unroll
            for (int r = 0; r < 4; ++r) {
                long rr = row + r;
                float rv;
                if constexpr (RESF32) rv = ((const float*)residv)[rr * 512 + col];
                else                  rv = (float)((const bf16*)residv)[rr * 512 + col];
                float v = acc[m][n][r] + bias[col] + rv;
                if constexpr (OUTF32) ((float*)outp)[rr * 512 + col] = v;
                else                  ((bf16*)outp)[rr * 512 + col] = (bf16)v;
            }
        }
}

// ---------------- Flash attention v9b (measured best): cross-tile pipeline, st ping-pong ----------------
#define NKT (NT / 64)

#define ATT_STAGE(J_, B_) do { \
    const bf16* ks_ = kbase + (size_t)(J_) * (64 * DH); \
    const bf16* vs_ = vbase + (J_) * 64; \
    gl_lds16(ks_,           &Ks[B_][(w * 8) * 64]); \
    gl_lds16(ks_ + 32 * DH, &Ks[B_][(32 + w * 8) * 64]); \
    gl_lds16(vs_,           &Vs[B_][(w * 8) * 64]); \
    gl_lds16(vs_ + 32 * NT, &Vs[B_][(32 + w * 8) * 64]); \
} while (0)

#define ATT_QK(B_, ST) do { \
    bf16x8 kf_[4][2]; \
    _Pragma("unroll") for (int kc = 0; kc < 4; ++kc) \
    _Pragma("unroll") for (int kk = 0; kk < 2; ++kk) \
        kf_[kc][kk] = *(const bf16x8*)&Ks[B_][(kc * 16 + c) * 64 + (((kk * 64 + g * 16) ^ xr) >> 1)]; \
    _Pragma("unroll") for (int kc = 0; kc < 4; ++kc) \
    _Pragma("unroll") for (int kk = 0; kk < 2; ++kk) \
        ST[kc] = __builtin_amdgcn_mfma_f32_16x16x32_bf16(kf_[kc][kk], qf[kk], ST[kc], 0, 0, 0); \
} while (0)

#define ATT_BODY(BUF, KT, SIN, SOUT) do { \
    bf16x8 vf[4][2]; \
    _Pragma("unroll") for (int dc = 0; dc < 4; ++dc) \
    _Pragma("unroll") for (int ks = 0; ks < 2; ++ks) \
        vf[dc][ks] = *(const bf16x8*)((const char*)&Vs[BUF][0] + (dc * 16 + c) * 128 + ((ks * 64 + g * 16) ^ xr)); \
    bf16x8 pf[2]; \
    _Pragma("unroll") for (int a = 0; a < 4; ++a) \
    _Pragma("unroll") for (int r = 0; r < 4; ++r) \
        pf[a >> 1][(a & 1) * 4 + r] = (bf16)exp2f(SIN[a][r]); \
    __syncthreads(); \
    if ((KT) + 2 < NKT) ATT_STAGE((KT) + 2, BUF); \
    _Pragma("unroll") for (int kc = 0; kc < 4; ++kc) SOUT[kc] = z4; \
    __builtin_amdgcn_s_setprio(1); \
    if ((KT) + 1 < NKT) ATT_QK((BUF) ^ 1, SOUT); \
    _Pragma("unroll") for (int ks = 0; ks < 2; ++ks) \
        sacc = __builtin_amdgcn_mfma_f32_16x16x32_bf16(ones8, pf[ks], sacc, 0, 0, 0); \
    _Pragma("unroll") for (int dc = 0; dc < 4; ++dc) \
    _Pragma("unroll") for (int ks = 0; ks < 2; ++ks) \
        oacc[dc] = __builtin_amdgcn_mfma_f32_16x16x32_bf16(vf[dc][ks], pf[ks], oacc[dc], 0, 0, 0); \
    __builtin_amdgcn_s_setprio(0); \
} while (0)

__global__ __launch_bounds__(256, 4) void attn_kernel(const bf16* __restrict__ qkv,
                                                      const bf16* __restrict__ vt,
                                                      bf16* __restrict__ O) {
    __shared__ bf16 Ks[2][64 * 64];
    __shared__ bf16 Vs[2][64 * 64];
    const int t = threadIdx.x, w = t >> 6, l = t & 63;
    const int g = l >> 4, c = l & 15;
    const int wg = blockIdx.x;
    const int xcd = wg & 7, rank = wg >> 3;
    const int bh = xcd + 8 * (rank >> 5);
    const int qt = rank & 31;
    const bf16* Qb = qkv + (long)bh * (NT * DH);
    const bf16* Kb = Qb + (long)(NB * HEADS) * (NT * DH);
    const bf16* Vtb = vt + (long)bh * (DH * NT);
    const int q0 = qt * 64 + w * 16;
    const int lr = l >> 3, lc = l & 7;
    const int sch = ((lc ^ lr) & 7) * 8;
    const int xr = (c & 7) << 4;

    const bf16* kbase = Kb + (long)(w * 8 + lr) * DH + sch;
    const bf16* vbase = Vtb + (long)(w * 8 + lr) * NT + sch;

    bf16x8 qf[2];
#pragma unroll
    for (int kk = 0; kk < 2; ++kk)
        qf[kk] = *(const bf16x8*)(Qb + (long)(q0 + c) * DH + kk * 32 + g * 8);

    bf16x8 ones8;
#pragma unroll
    for (int j = 0; j < 8; ++j) ones8[j] = (bf16)1.0f;
    const f32x4 z4 = {};

    f32x4 oacc[4] = {};
    f32x4 sacc = {};
    f32x4 st0[4] = {}, st1[4];

    ATT_STAGE(0, 0);
    ATT_STAGE(1, 1);
    __syncthreads();
    ATT_QK(0, st0);

#pragma unroll 1
    for (int kt2 = 0; kt2 < NKT / 2; ++kt2) {
        ATT_BODY(0, kt2 * 2,     st0, st1);
        ATT_BODY(1, kt2 * 2 + 1, st1, st0);
    }

    float inv = 1.f / sacc[0];

    char* ol = (char*)&Ks[0][0] + w * 2048;
#pragma unroll
    for (int dc = 0; dc < 4; ++dc) {
        bf16x4 o4;
#pragma unroll
        for (int r = 0; r < 4; ++r) o4[r] = (bf16)(oacc[dc][r] * inv);
        *(bf16x4*)(ol + c * 128 + ((dc * 32 + g * 8) ^ xr)) = o4;
    }
    __builtin_amdgcn_s_waitcnt(0);  // lgkmcnt(0): wave-private region
    const int orow = l >> 2, oc = (l & 3) * 16;
    const int bb = bh >> 3, hh = bh & 7;
    long tok = (long)bb * NT + q0 + orow;
    bf16* og = O + tok * DIM + hh * 64 + oc;
    const int xr2 = (orow & 7) << 4;
    bf16x8 v0 = *(const bf16x8*)(ol + orow * 128 + ((oc * 2) ^ xr2));
    bf16x8 v1 = *(const bf16x8*)(ol + orow * 128 + ((oc * 2 + 16) ^ xr2));
    *(bf16x8*)og = v0;
    *(bf16x8*)(og + 8) = v1;
}

extern "C" void kernel_launch(void* const* d_in, const int* in_sizes, int n_in,
                              void* d_out, int out_size, void* d_ws, size_t ws_size,
                              hipStream_t stream) {
    const float* x      = (const float*)d_in[0];
    const float* ln1_w  = (const float*)d_in[1];
    const float* ln1_b  = (const float*)d_in[2];
    const float* qkv_w  = (const float*)d_in[3];
    const float* proj_w = (const float*)d_in[4];
    const float* proj_b = (const float*)d_in[5];
    const float* ln2_w  = (const float*)d_in[6];
    const float* ln2_b  = (const float*)d_in[7];
    const float* fc1_w  = (const float*)d_in[8];
    const float* fc1_b  = (const float*)d_in[9];
    const float* fc2_w  = (const float*)d_in[10];
    const float* fc2_b  = (const float*)d_in[11];
    float* Xout = (float*)d_out;                      // written once, by layer-3 fc2

    char* ws = (char*)d_ws;
    bf16* h_bf   = (bf16*)(ws);                       // 8 MB (h; also attn O — disjoint lifetimes)
    bf16* scr_bf = (bf16*)(ws + (size_t)(8  << 20));  // qkv 24 MB | gelu 32 MB
    bf16* vt_bf  = (bf16*)(ws + (size_t)(32 << 20));  // 8 MB (dead before fc1 overwrites)
    bf16* X_bf   = (bf16*)(ws + (size_t)(40 << 20));  // 8 MB bf16 residual stream
    bf16* o_bf   = h_bf;                              // attn output aliases h (h dead after qkv)
    bf16* w_qkv  = (bf16*)(ws + (size_t)(48 << 20));
    bf16* w_proj = w_qkv  + (size_t)4 * 1536 * 512;
    bf16* w_fc1  = w_proj + (size_t)4 * 512 * 512;
    bf16* w_fc2  = w_fc1  + (size_t)4 * 2048 * 512;

    cvt_all_kernel<<<12288, 256, 0, stream>>>(qkv_w, proj_w, fc1_w, fc2_w,
                                              w_qkv, w_proj, w_fc1, w_fc2);

    for (int i = 0; i < 4; ++i) {
        // LN1: layer 0 reads fp32 input x; later layers read bf16 X stream
        if (i == 0)
            ln_kernel<true><<<M_TOK / 4, 256, 0, stream>>>(x, ln1_w, ln1_b, h_bf);
        else
            ln_kernel<false><<<M_TOK / 4, 256, 0, stream>>>(X_bf, ln1_w + i * 512, ln1_b + i * 512, h_bf);
        gemm128<0, 512><<<(M_TOK / 128) * (1536 / 128), 256, 0, stream>>>(
            h_bf, w_qkv + (size_t)i * 1536 * 512, nullptr, nullptr, scr_bf, 1536, vt_bf);
        attn_kernel<<<1024, 256, 0, stream>>>(scr_bf, vt_bf, o_bf);
        // proj: resid = x (fp32) at layer 0, else bf16 X; out = bf16 X
        if (i == 0)
            gemm_n64<512, true, false><<<dim3(8, 64), 256, 0, stream>>>(
                o_bf, w_proj, proj_b, x, X_bf);
        else
            gemm_n64<512, false, false><<<dim3(8, 64), 256, 0, stream>>>(
                o_bf, w_proj + (size_t)i * 512 * 512, proj_b + i * 512, X_bf, X_bf);
        ln_kernel<false><<<M_TOK / 4, 256, 0, stream>>>(X_bf, ln2_w + i * 512, ln2_b + i * 512, h_bf);
        gemm128<2, 512><<<(M_TOK / 128) * (2048 / 128), 256, 0, stream>>>(
            h_bf, w_fc1 + (size_t)i * 2048 * 512, fc1_b + i * 2048, nullptr, scr_bf, 2048, nullptr);
        // fc2: layers 0-2 keep bf16 X stream; layer 3 writes fp32 d_out
        if (i < 3)
            gemm_n64<2048, false, false><<<dim3(8, 64), 256, 0, stream>>>(
                scr_bf, w_fc2 + (size_t)i * 512 * 2048, fc2_b + i * 512, X_bf, X_bf);
        else
            gemm_n64<2048, false, true><<<dim3(8, 64), 256, 0, stream>>>(
                scr_bf, w_fc2 + (size_t)i * 512 * 2048, fc2_b + i * 512, X_bf, Xout);
    }
}

// Round 18
// 698.406 us; speedup vs baseline: 1.0307x; 1.0006x over previous
//
#include <hip/hip_runtime.h>
#include <hip/hip_bf16.h>
#include <math.h>

#define NB 4
#define HEADS 8
#define DIM 512
#define MLP 2048
#define NT 2048
#define DH 64
#define M_TOK (NB*NT)

typedef __bf16 bf16;
typedef __bf16 bf16x2 __attribute__((ext_vector_type(2)));
typedef __bf16 bf16x4 __attribute__((ext_vector_type(4)));
typedef __bf16 bf16x8 __attribute__((ext_vector_type(8)));
typedef float f32x4 __attribute__((ext_vector_type(4)));

__device__ __forceinline__ void gl_lds16(const void* g, void* l) {
    __builtin_amdgcn_global_load_lds((const __attribute__((address_space(1))) unsigned int*)g,
                                     (__attribute__((address_space(3))) unsigned int*)l, 16, 0, 0);
}

#define BARRIER() do { __builtin_amdgcn_s_barrier(); asm volatile("" ::: "memory"); } while(0)
#define WAIT_VM4() asm volatile("s_waitcnt vmcnt(4)" ::: "memory")
#define WAIT_VM0() asm volatile("s_waitcnt vmcnt(0)" ::: "memory")

// tanh-form GELU: ~8 VALU instrs vs erff's ~20+; max |err| ~5e-4; exact at +-inf.
__device__ __forceinline__ float fast_gelu(float u) {
    float u2 = u * u;
    float y  = u * __builtin_fmaf(u2, 0.044715f, 1.0f);
    float e  = exp2f(y * 2.3021839f);          // exp(2*0.79788456*y)
    float r  = __builtin_amdgcn_rcpf(e + 1.0f);
    return u - u * r;                           // u * e/(e+1)
}

// ---------------- fused fp32 -> bf16 weight conversion (all 4 tensors, 1 launch) ----------------
__global__ void cvt_all_kernel(const float* __restrict__ qkv_w, const float* __restrict__ proj_w,
                               const float* __restrict__ fc1_w, const float* __restrict__ fc2_w,
                               bf16* __restrict__ w_qkv, bf16* __restrict__ w_proj,
                               bf16* __restrict__ w_fc1, bf16* __restrict__ w_fc2) {
    int b = blockIdx.x;
    const float* src;
    bf16* dst;
    int base;
    if (b < 3072)      { src = qkv_w;  dst = w_qkv;  base = b; }
    else if (b < 4096) { src = proj_w; dst = w_proj; base = b - 3072; }
    else if (b < 8192) { src = fc1_w;  dst = w_fc1;  base = b - 4096; }
    else               { src = fc2_w;  dst = w_fc2;  base = b - 8192; }
    long i = ((long)base * 256 + threadIdx.x) * 4;
    float4 v = *(const float4*)(src + i);
    bf16x4 o;
    o[0] = (bf16)v.x; o[1] = (bf16)v.y; o[2] = (bf16)v.z; o[3] = (bf16)v.w;
    *(bf16x4*)(dst + i) = o;
}

// ---------------- LayerNorm (one wave per row of 512); input fp32 or bf16 ----------------
template<bool INF32>
__global__ void ln_kernel(const void* __restrict__ Xv, const float* __restrict__ gam,
                          const float* __restrict__ bet, bf16* __restrict__ out) {
    int w = threadIdx.x >> 6, l = threadIdx.x & 63;
    long row = (long)blockIdx.x * 4 + w;
    float xv[8];
    if constexpr (INF32) {
        const float* xp = (const float*)Xv + row * DIM + l * 8;
        float4 a = *(const float4*)xp;
        float4 b = *(const float4*)(xp + 4);
        xv[0] = a.x; xv[1] = a.y; xv[2] = a.z; xv[3] = a.w;
        xv[4] = b.x; xv[5] = b.y; xv[6] = b.z; xv[7] = b.w;
    } else {
        bf16x8 v = *(const bf16x8*)((const bf16*)Xv + row * DIM + l * 8);
#pragma unroll
        for (int j = 0; j < 8; ++j) xv[j] = (float)v[j];
    }
    float s1 = 0.f, s2 = 0.f;
#pragma unroll
    for (int j = 0; j < 8; ++j) { s1 += xv[j]; s2 += xv[j] * xv[j]; }
#pragma unroll
    for (int off = 32; off; off >>= 1) { s1 += __shfl_xor(s1, off); s2 += __shfl_xor(s2, off); }
    float mean = s1 * (1.f / 512.f);
    float var  = s2 * (1.f / 512.f) - mean * mean;
    float rstd = rsqrtf(var + 1e-5f);
    float ga[8], be[8];
    {
        float4 g0 = *(const float4*)(gam + l * 8), g1 = *(const float4*)(gam + l * 8 + 4);
        float4 b0 = *(const float4*)(bet + l * 8), b1 = *(const float4*)(bet + l * 8 + 4);
        ga[0] = g0.x; ga[1] = g0.y; ga[2] = g0.z; ga[3] = g0.w;
        ga[4] = g1.x; ga[5] = g1.y; ga[6] = g1.z; ga[7] = g1.w;
        be[0] = b0.x; be[1] = b0.y; be[2] = b0.z; be[3] = b0.w;
        be[4] = b1.x; be[5] = b1.y; be[6] = b1.z; be[7] = b1.w;
    }
    bf16x8 o;
#pragma unroll
    for (int j = 0; j < 8; ++j) o[j] = (bf16)((xv[j] - mean) * rstd * ga[j] + be[j]);
    *(bf16x8*)(out + row * DIM + l * 8) = o;
}

// ================= 128x128 8-phase GEMM (4 waves, BK=64, dbuf) — qkv / fc1 =================
#define G_LOADA(AF, B_, MQ) do { \
  _Pragma("unroll") for (int mi_ = 0; mi_ < 2; ++mi_) \
  _Pragma("unroll") for (int kk_ = 0; kk_ < 2; ++kk_) { \
    int row_ = wr * 64 + ((MQ) * 2 + mi_) * 16 + c; \
    AF[mi_][kk_] = *(const bf16x8*)&Abuf[B_][row_ * 64 + (((kk_ * 64 + g * 16) ^ sw) >> 1)]; \
  } } while (0)

#define G_LOADB(BF, B_, NQ) do { \
  _Pragma("unroll") for (int ni_ = 0; ni_ < 2; ++ni_) \
  _Pragma("unroll") for (int kk_ = 0; kk_ < 2; ++kk_) { \
    int row_ = wc * 64 + ((NQ) * 2 + ni_) * 16 + c; \
    BF[ni_][kk_] = *(const bf16x8*)&Bbuf[B_][row_ * 64 + (((kk_ * 64 + g * 16) ^ sw) >> 1)]; \
  } } while (0)

#define G_MFMA(AF, BF, MQ, NQ) do { \
  __builtin_amdgcn_s_setprio(1); \
  _Pragma("unroll") for (int mi_ = 0; mi_ < 2; ++mi_) \
  _Pragma("unroll") for (int ni_ = 0; ni_ < 2; ++ni_) \
  _Pragma("unroll") for (int kk_ = 0; kk_ < 2; ++kk_) \
    acc[(MQ)*2+mi_][(NQ)*2+ni_] = __builtin_amdgcn_mfma_f32_16x16x32_bf16( \
        AF[mi_][kk_], BF[ni_][kk_], acc[(MQ)*2+mi_][(NQ)*2+ni_], 0, 0, 0); \
  __builtin_amdgcn_s_setprio(0); \
} while (0)

#define G_STAGE_A(J_, H_) do { int j_ = (J_); if (j_ < nkt) { \
  bf16* db_ = Abuf[j_ & 1]; const bf16* sb_ = Aptr + (size_t)j_ * 64 + coloff; \
  _Pragma("unroll") for (int q_ = 0; q_ < 2; ++q_) { \
    int rw_ = q_ * 64 + (H_) * 32 + (w << 3); \
    gl_lds16(sb_ + (size_t)(arow0 + rw_ + lr) * KN, db_ + rw_ * 64); \
  } } } while (0)

#define G_STAGE_B(J_, H_) do { int j_ = (J_); if (j_ < nkt) { \
  bf16* db_ = Bbuf[j_ & 1]; const bf16* sb_ = Wptr + (size_t)j_ * 64 + coloff; \
  _Pragma("unroll") for (int q_ = 0; q_ < 2; ++q_) { \
    int rw_ = q_ * 64 + (H_) * 32 + (w << 3); \
    gl_lds16(sb_ + (size_t)(bcol0 + rw_ + lr) * KN, db_ + rw_ * 64); \
  } } } while (0)

// EPI 0: QKV scatter (Q pre-scaled by 0.125*log2e; V transposed to vt)
// EPI 2: +bias fast-GELU -> bf16 (fc1)
template<int EPI, int KN>
__global__ __launch_bounds__(256, 2) void gemm128(const bf16* __restrict__ Aptr,
                                                  const bf16* __restrict__ Wptr,
                                                  const float* __restrict__ bias,
                                                  const float* __restrict__ resid,
                                                  void* outp, int N, bf16* __restrict__ vtout) {
    __shared__ bf16 Abuf[2][128 * 64];
    __shared__ bf16 Bbuf[2][128 * 64];
    const int t = threadIdx.x, w = t >> 6, l = t & 63;
    const int wr = w >> 1, wc = w & 1, g = l >> 4, c = l & 15;
    const int sw = (c & 7) << 4;
    const int lr = l >> 3;
    const int coloff = ((l & 7) ^ lr) << 3;

    int nwg = gridDim.x, bid = blockIdx.x;
    int q8 = nwg >> 3, r8 = nwg & 7;
    int xcd = bid & 7, rank = bid >> 3;
    int swz = (xcd < r8) ? xcd * (q8 + 1) + rank : r8 * (q8 + 1) + (xcd - r8) * q8 + rank;
    int tiles_n = N >> 7;
    long arow0 = (long)(swz / tiles_n) * 128;
    long bcol0 = (long)(swz % tiles_n) * 128;

    const int nkt = KN / 64;
    const int niter = nkt / 2;
    f32x4 acc[4][4] = {};
    bf16x8 af[2][2], bn0[2][2], bn1[2][2];

    G_STAGE_A(0, 0); G_STAGE_B(0, 0); G_STAGE_A(0, 1); G_STAGE_B(0, 1);
    G_STAGE_A(1, 0); G_STAGE_B(1, 0);

#pragma unroll 1
    for (int tt = 0; tt < niter; ++tt) {
        const int J0 = 2 * tt, J1 = 2 * tt + 1;
        const bool last = (tt == niter - 1);
        WAIT_VM4(); BARRIER();
        G_LOADA(af, 0, 0); G_LOADB(bn0, 0, 0);
        G_STAGE_A(J0 + 1, 1);
        G_MFMA(af, bn0, 0, 0);
        BARRIER();
        G_LOADB(bn1, 0, 1);
        G_STAGE_B(J0 + 1, 1);
        G_MFMA(af, bn1, 0, 1);
        BARRIER();
        G_LOADA(af, 0, 1);
        G_STAGE_A(J0 + 2, 0);
        G_MFMA(af, bn0, 1, 0);
        BARRIER();
        G_STAGE_B(J0 + 2, 0);
        G_MFMA(af, bn1, 1, 1);
        BARRIER();
        if (last) { WAIT_VM0(); } else { WAIT_VM4(); }
        BARRIER();
        G_LOADA(af, 1, 0); G_LOADB(bn0, 1, 0);
        G_STAGE_A(J1 + 1, 1);
        G_MFMA(af, bn0, 0, 0);
        BARRIER();
        G_LOADB(bn1, 1, 1);
        G_STAGE_B(J1 + 1, 1);
        G_MFMA(af, bn1, 0, 1);
        BARRIER();
        G_LOADA(af, 1, 1);
        G_STAGE_A(J1 + 2, 0);
        G_MFMA(af, bn0, 1, 0);
        BARRIER();
        G_STAGE_B(J1 + 2, 0);
        G_MFMA(af, bn1, 1, 1);
        BARRIER();
    }

    if constexpr (EPI == 0) {
        const int s = (int)(bcol0 >> 9);
        const float qscale = 0.18033688011112042f;   // 0.125 * log2(e)
        if (s == 2) {
#pragma unroll
            for (int m = 0; m < 4; ++m)
#pragma unroll
                for (int n = 0; n < 4; ++n) {
                    int col = (int)(bcol0 + wc * 64 + n * 16 + c);
                    int d = col & 63, hh = (col >> 6) & 7;
                    long row = arow0 + wr * 64 + m * 16 + g * 4;
                    int bb = (int)(row >> 11), nn = (int)(row & 2047);
                    bf16x4 o4;
#pragma unroll
                    for (int r = 0; r < 4; ++r) o4[r] = (bf16)acc[m][n][r];
                    *(bf16x4*)(vtout + ((long)(bb * 8 + hh) * 64 + d) * 2048 + nn) = o4;
                }
        } else {
            const float sc = (s == 0) ? qscale : 1.0f;
#pragma unroll
            for (int m = 0; m < 4; ++m)
#pragma unroll
                for (int n = 0; n < 4; ++n) {
                    int col = (int)(bcol0 + wc * 64 + n * 16 + c);
                    int hh = (col >> 6) & 7, d = col & 63;
                    long row = arow0 + wr * 64 + m * 16 + g * 4;
#pragma unroll
                    for (int r = 0; r < 4; ++r) {
                        long rr = row + r;
                        int bb = (int)(rr >> 11), nn = (int)(rr & 2047);
                        ((bf16*)outp)[(((long)(s * NB + bb) * HEADS + hh) * NT + nn) * DH + d] =
                            (bf16)(acc[m][n][r] * sc);
                    }
                }
        }
    } else {
#pragma unroll
        for (int m = 0; m < 4; ++m)
#pragma unroll
            for (int n = 0; n < 4; ++n) {
                long row = arow0 + wr * 64 + m * 16 + g * 4;
                long col = bcol0 + wc * 64 + n * 16 + c;
#pragma unroll
                for (int r = 0; r < 4; ++r) {
                    long rr = row + r;
                    float u = acc[m][n][r] + bias[col];
                    ((bf16*)outp)[rr * N + col] = (bf16)fast_gelu(u);
                }
            }
    }
}

// ======== 128x64-tile 2-phase GEMM (m97 structure), N=512 out (proj / fc2) ========
// RESF32: residual read fp32 (layer-0 proj reads x); else bf16 X stream.
// OUTF32: write fp32 (layer-3 fc2 -> d_out); else bf16 X stream.
template<int KN, bool RESF32, bool OUTF32>
__global__ __launch_bounds__(256, 2) void gemm_n64(const bf16* __restrict__ A,
                                                   const bf16* __restrict__ W,
                                                   const float* __restrict__ bias,
                                                   const void* __restrict__ residv,
                                                   void* __restrict__ outp) {
    __shared__ bf16 As[128 * 64];
    __shared__ bf16 Bs[64 * 64];
    const int t = threadIdx.x, w = t >> 6, l = t & 63;
    const int wr = w >> 1, wc = w & 1, g = l >> 4, c = l & 15;
    const long arow0 = (long)blockIdx.y * 128;
    const long bcol0 = (long)blockIdx.x * 64;
    f32x4 acc[4][2] = {};
    const int lrow = l >> 3, lcol = (l & 7) * 8;
    const bf16* Ab = A + (arow0 + lrow) * (long)KN + lcol;
    const bf16* Wb = W + (bcol0 + lrow) * (long)KN + lcol;
    for (int k0 = 0; k0 < KN; k0 += 64) {
#pragma unroll
        for (int q = 0; q < 4; ++q)
            gl_lds16(Ab + (long)(w * 4 + q) * 8 * KN + k0, &As[(w * 4 + q) * 512]);
#pragma unroll
        for (int q = 0; q < 2; ++q)
            gl_lds16(Wb + (long)(w * 2 + q) * 8 * KN + k0, &Bs[(w * 2 + q) * 512]);
        __syncthreads();
#pragma unroll
        for (int kk = 0; kk < 2; ++kk) {
            bf16x8 afv[4], bfr[2];
#pragma unroll
            for (int m = 0; m < 4; ++m)
                afv[m] = *(const bf16x8*)&As[(wr * 64 + m * 16 + c) * 64 + kk * 32 + g * 8];
#pragma unroll
            for (int n = 0; n < 2; ++n)
                bfr[n] = *(const bf16x8*)&Bs[(wc * 32 + n * 16 + c) * 64 + kk * 32 + g * 8];
#pragma unroll
            for (int m = 0; m < 4; ++m)
#pragma unroll
                for (int n = 0; n < 2; ++n)
                    acc[m][n] = __builtin_amdgcn_mfma_f32_16x16x32_bf16(afv[m], bfr[n], acc[m][n], 0, 0, 0);
        }
        __syncthreads();
    }
#pragma unroll
    for (int m = 0; m < 4; ++m)
#pragma unroll
        for (int n = 0; n < 2; ++n) {
            long row = arow0 + wr * 64 + m * 16 + g * 4;
            long col = bcol0 + wc * 32 + n * 16 + c;
#pragma unroll
            for (int r = 0; r < 4; ++r) {
                long rr = row + r;
                float rv;
                if constexpr (RESF32) rv = ((const float*)residv)[rr * 512 + col];
                else                  rv = (float)((const bf16*)residv)[rr * 512 + col];
                float v = acc[m][n][r] + bias[col] + rv;
                if constexpr (OUTF32) ((float*)outp)[rr * 512 + col] = v;
                else                  ((bf16*)outp)[rr * 512 + col] = (bf16)v;
            }
        }
}

// ---------------- Flash attention v9b (measured best): cross-tile pipeline, st ping-pong ----------------
#define NKT (NT / 64)

#define ATT_STAGE(J_, B_) do { \
    const bf16* ks_ = kbase + (size_t)(J_) * (64 * DH); \
    const bf16* vs_ = vbase + (J_) * 64; \
    gl_lds16(ks_,           &Ks[B_][(w * 8) * 64]); \
    gl_lds16(ks_ + 32 * DH, &Ks[B_][(32 + w * 8) * 64]); \
    gl_lds16(vs_,           &Vs[B_][(w * 8) * 64]); \
    gl_lds16(vs_ + 32 * NT, &Vs[B_][(32 + w * 8) * 64]); \
} while (0)

#define ATT_QK(B_, ST) do { \
    bf16x8 kf_[4][2]; \
    _Pragma("unroll") for (int kc = 0; kc < 4; ++kc) \
    _Pragma("unroll") for (int kk = 0; kk < 2; ++kk) \
        kf_[kc][kk] = *(const bf16x8*)&Ks[B_][(kc * 16 + c) * 64 + (((kk * 64 + g * 16) ^ xr) >> 1)]; \
    _Pragma("unroll") for (int kc = 0; kc < 4; ++kc) \
    _Pragma("unroll") for (int kk = 0; kk < 2; ++kk) \
        ST[kc] = __builtin_amdgcn_mfma_f32_16x16x32_bf16(kf_[kc][kk], qf[kk], ST[kc], 0, 0, 0); \
} while (0)

#define ATT_BODY(BUF, KT, SIN, SOUT) do { \
    bf16x8 vf[4][2]; \
    _Pragma("unroll") for (int dc = 0; dc < 4; ++dc) \
    _Pragma("unroll") for (int ks = 0; ks < 2; ++ks) \
        vf[dc][ks] = *(const bf16x8*)((const char*)&Vs[BUF][0] + (dc * 16 + c) * 128 + ((ks * 64 + g * 16) ^ xr)); \
    bf16x8 pf[2]; \
    _Pragma("unroll") for (int a = 0; a < 4; ++a) \
    _Pragma("unroll") for (int r = 0; r < 4; ++r) \
        pf[a >> 1][(a & 1) * 4 + r] = (bf16)exp2f(SIN[a][r]); \
    __syncthreads(); \
    if ((KT) + 2 < NKT) ATT_STAGE((KT) + 2, BUF); \
    _Pragma("unroll") for (int kc = 0; kc < 4; ++kc) SOUT[kc] = z4; \
    __builtin_amdgcn_s_setprio(1); \
    if ((KT) + 1 < NKT) ATT_QK((BUF) ^ 1, SOUT); \
    _Pragma("unroll") for (int ks = 0; ks < 2; ++ks) \
        sacc = __builtin_amdgcn_mfma_f32_16x16x32_bf16(ones8, pf[ks], sacc, 0, 0, 0); \
    _Pragma("unroll") for (int dc = 0; dc < 4; ++dc) \
    _Pragma("unroll") for (int ks = 0; ks < 2; ++ks) \
        oacc[dc] = __builtin_amdgcn_mfma_f32_16x16x32_bf16(vf[dc][ks], pf[ks], oacc[dc], 0, 0, 0); \
    __builtin_amdgcn_s_setprio(0); \
} while (0)

__global__ __launch_bounds__(256, 4) void attn_kernel(const bf16* __restrict__ qkv,
                                                      const bf16* __restrict__ vt,
                                                      bf16* __restrict__ O) {
    __shared__ bf16 Ks[2][64 * 64];
    __shared__ bf16 Vs[2][64 * 64];
    const int t = threadIdx.x, w = t >> 6, l = t & 63;
    const int g = l >> 4, c = l & 15;
    const int wg = blockIdx.x;
    const int xcd = wg & 7, rank = wg >> 3;
    const int bh = xcd + 8 * (rank >> 5);
    const int qt = rank & 31;
    const bf16* Qb = qkv + (long)bh * (NT * DH);
    const bf16* Kb = Qb + (long)(NB * HEADS) * (NT * DH);
    const bf16* Vtb = vt + (long)bh * (DH * NT);
    const int q0 = qt * 64 + w * 16;
    const int lr = l >> 3, lc = l & 7;
    const int sch = ((lc ^ lr) & 7) * 8;
    const int xr = (c & 7) << 4;

    const bf16* kbase = Kb + (long)(w * 8 + lr) * DH + sch;
    const bf16* vbase = Vtb + (long)(w * 8 + lr) * NT + sch;

    bf16x8 qf[2];
#pragma unroll
    for (int kk = 0; kk < 2; ++kk)
        qf[kk] = *(const bf16x8*)(Qb + (long)(q0 + c) * DH + kk * 32 + g * 8);

    bf16x8 ones8;
#pragma unroll
    for (int j = 0; j < 8; ++j) ones8[j] = (bf16)1.0f;
    const f32x4 z4 = {};

    f32x4 oacc[4] = {};
    f32x4 sacc = {};
    f32x4 st0[4] = {}, st1[4];

    ATT_STAGE(0, 0);
    ATT_STAGE(1, 1);
    __syncthreads();
    ATT_QK(0, st0);

#pragma unroll 1
    for (int kt2 = 0; kt2 < NKT / 2; ++kt2) {
        ATT_BODY(0, kt2 * 2,     st0, st1);
        ATT_BODY(1, kt2 * 2 + 1, st1, st0);
    }

    float inv = 1.f / sacc[0];

    char* ol = (char*)&Ks[0][0] + w * 2048;
#pragma unroll
    for (int dc = 0; dc < 4; ++dc) {
        bf16x4 o4;
#pragma unroll
        for (int r = 0; r < 4; ++r) o4[r] = (bf16)(oacc[dc][r] * inv);
        *(bf16x4*)(ol + c * 128 + ((dc * 32 + g * 8) ^ xr)) = o4;
    }
    __builtin_amdgcn_s_waitcnt(0);  // lgkmcnt(0): wave-private region
    const int orow = l >> 2, oc = (l & 3) * 16;
    const int bb = bh >> 3, hh = bh & 7;
    long tok = (long)bb * NT + q0 + orow;
    bf16* og = O + tok * DIM + hh * 64 + oc;
    const int xr2 = (orow & 7) << 4;
    bf16x8 v0 = *(const bf16x8*)(ol + orow * 128 + ((oc * 2) ^ xr2));
    bf16x8 v1 = *(const bf16x8*)(ol + orow * 128 + ((oc * 2 + 16) ^ xr2));
    *(bf16x8*)og = v0;
    *(bf16x8*)(og + 8) = v1;
}

extern "C" void kernel_launch(void* const* d_in, const int* in_sizes, int n_in,
                              void* d_out, int out_size, void* d_ws, size_t ws_size,
                              hipStream_t stream) {
    const float* x      = (const float*)d_in[0];
    const float* ln1_w  = (const float*)d_in[1];
    const float* ln1_b  = (const float*)d_in[2];
    const float* qkv_w  = (const float*)d_in[3];
    const float* proj_w = (const float*)d_in[4];
    const float* proj_b = (const float*)d_in[5];
    const float* ln2_w  = (const float*)d_in[6];
    const float* ln2_b  = (const float*)d_in[7];
    const float* fc1_w  = (const float*)d_in[8];
    const float* fc1_b  = (const float*)d_in[9];
    const float* fc2_w  = (const float*)d_in[10];
    const float* fc2_b  = (const float*)d_in[11];
    float* Xout = (float*)d_out;                      // written once, by layer-3 fc2

    char* ws = (char*)d_ws;
    bf16* h_bf   = (bf16*)(ws);                       // 8 MB (h; also attn O — disjoint lifetimes)
    bf16* scr_bf = (bf16*)(ws + (size_t)(8  << 20));  // qkv 24 MB | gelu 32 MB
    bf16* vt_bf  = (bf16*)(ws + (size_t)(32 << 20));  // 8 MB (dead before fc1 overwrites)
    bf16* X_bf   = (bf16*)(ws + (size_t)(40 << 20));  // 8 MB bf16 residual stream
    bf16* o_bf   = h_bf;                              // attn output aliases h (h dead after qkv)
    bf16* w_qkv  = (bf16*)(ws + (size_t)(48 << 20));
    bf16* w_proj = w_qkv  + (size_t)4 * 1536 * 512;
    bf16* w_fc1  = w_proj + (size_t)4 * 512 * 512;
    bf16* w_fc2  = w_fc1  + (size_t)4 * 2048 * 512;

    cvt_all_kernel<<<12288, 256, 0, stream>>>(qkv_w, proj_w, fc1_w, fc2_w,
                                              w_qkv, w_proj, w_fc1, w_fc2);

    for (int i = 0; i < 4; ++i) {
        // LN1: layer 0 reads fp32 input x; later layers read bf16 X stream
        if (i == 0)
            ln_kernel<true><<<M_TOK / 4, 256, 0, stream>>>(x, ln1_w, ln1_b, h_bf);
        else
            ln_kernel<false><<<M_TOK / 4, 256, 0, stream>>>(X_bf, ln1_w + i * 512, ln1_b + i * 512, h_bf);
        gemm128<0, 512><<<(M_TOK / 128) * (1536 / 128), 256, 0, stream>>>(
            h_bf, w_qkv + (size_t)i * 1536 * 512, nullptr, nullptr, scr_bf, 1536, vt_bf);
        attn_kernel<<<1024, 256, 0, stream>>>(scr_bf, vt_bf, o_bf);
        // proj: resid = x (fp32) at layer 0, else bf16 X; out = bf16 X
        if (i == 0)
            gemm_n64<512, true, false><<<dim3(8, 64), 256, 0, stream>>>(
                o_bf, w_proj, proj_b, x, X_bf);
        else
            gemm_n64<512, false, false><<<dim3(8, 64), 256, 0, stream>>>(
                o_bf, w_proj + (size_t)i * 512 * 512, proj_b + i * 512, X_bf, X_bf);
        ln_kernel<false><<<M_TOK / 4, 256, 0, stream>>>(X_bf, ln2_w + i * 512, ln2_b + i * 512, h_bf);
        gemm128<2, 512><<<(M_TOK / 128) * (2048 / 128), 256, 0, stream>>>(
            h_bf, w_fc1 + (size_t)i * 2048 * 512, fc1_b + i * 2048, nullptr, scr_bf, 2048, nullptr);
        // fc2: layers 0-2 keep bf16 X stream; layer 3 writes fp32 d_out
        if (i < 3)
            gemm_n64<2048, false, false><<<dim3(8, 64), 256, 0, stream>>>(
                scr_bf, w_fc2 + (size_t)i * 512 * 2048, fc2_b + i * 512, X_bf, X_bf);
        else
            gemm_n64<2048, false, true><<<dim3(8, 64), 256, 0, stream>>>(
                scr_bf, w_fc2 + (size_t)i * 512 * 2048, fc2_b + i * 512, X_bf, Xout);
    }
}